// Round 3
// baseline (1015.458 us; speedup 1.0000x reference)
//
#include <hip/hip_runtime.h>
#include <hip/hip_bf16.h>

// QMixer forward, MI355X gfx950.  ALL inputs/outputs are fp32 (reference dtype).
// Shapes: B=128 S=128 A=8 En=8 E=16 NFal=32 NFen=16 D=64 Da=128 M=32 H=64.
// One 64-lane wave per (b,s) site.

#define B_   128
#define S_   128
#define A_   8
#define EN_  8
#define E_   16
#define D_   64
#define DA_  128
#define M_   32
#define H_   64
#define NFAL 32
#define NFEN 16

__global__ __launch_bounds__(64)
void qmix_fwd(const float* __restrict__ agent_qs,
              const float* __restrict__ ally,
              const float* __restrict__ enemy,
              const float* __restrict__ W_al, const float* __restrict__ b_al,
              const float* __restrict__ W_en, const float* __restrict__ b_en,
              const float* __restrict__ Wq,   const float* __restrict__ bq,
              const float* __restrict__ Wk,   const float* __restrict__ bk,
              const float* __restrict__ w1_W1, const float* __restrict__ w1_b1,
              const float* __restrict__ w1_W2, const float* __restrict__ w1_b2,
              const float* __restrict__ wf_W1, const float* __restrict__ wf_b1,
              const float* __restrict__ wf_W2, const float* __restrict__ wf_b2,
              const float* __restrict__ hb_W,  const float* __restrict__ hb_b,
              const float* __restrict__ v_W1,  const float* __restrict__ v_b1,
              const float* __restrict__ v_W2,  const float* __restrict__ v_b2,
              float* __restrict__ out)
{
    const int site = blockIdx.x;       // b*S + s
    const int b    = site >> 7;        // site / S_
    const int s    = site & (S_ - 1);
    const int lane = threadIdx.x;      // 0..63

    __shared__ float s_ent[E_][D_];        // entity embeddings
    __shared__ float s_q[E_][DA_ + 1];     // +1 pad: bank-conflict-free column reads
    __shared__ float s_k[E_][DA_ + 1];
    __shared__ float s_en[E_][E_ + 1];     // energy, +1 pad
    __shared__ float s_colM[E_], s_colS[E_];
    __shared__ float s_amean[E_];
    __shared__ float s_aout[D_];
    __shared__ float s_h[H_];              // hypernet hidden (reused)
    __shared__ float s_feat[NFAL];
    __shared__ float s_red[64];

    // ---------- entity encoders ----------
    for (int e = 0; e < A_; ++e) {
        if (lane < NFAL)
            s_feat[lane] = ally[((e * B_ + b) * S_ + s) * NFAL + lane];
        __syncthreads();
        float acc = b_al[lane];
        #pragma unroll
        for (int f = 0; f < NFAL; ++f)
            acc += s_feat[f] * W_al[f * D_ + lane];
        s_ent[e][lane] = acc;
        __syncthreads();
    }
    for (int e = 0; e < EN_; ++e) {
        if (lane < NFEN)
            s_feat[lane] = enemy[((e * B_ + b) * S_ + s) * NFEN + lane];
        __syncthreads();
        float acc = b_en[lane];
        #pragma unroll
        for (int f = 0; f < NFEN; ++f)
            acc += s_feat[f] * W_en[f * D_ + lane];
        s_ent[A_ + e][lane] = acc;
        __syncthreads();
    }

    // ---------- q,k projections: [16,64] @ [64,128] ----------
    const float inv_sqrt_da = 0.08838834764831845f;  // 1/sqrt(128), folded into q
    const float bq0 = bq[lane], bq1 = bq[lane + 64];
    const float bk0 = bk[lane], bk1 = bk[lane + 64];
    for (int e = 0; e < E_; ++e) {
        float q0 = bq0, q1 = bq1, k0 = bk0, k1 = bk1;
        #pragma unroll 8
        for (int d = 0; d < D_; ++d) {
            const float ed = s_ent[e][d];
            q0 += ed * Wq[d * DA_ + lane];
            q1 += ed * Wq[d * DA_ + lane + 64];
            k0 += ed * Wk[d * DA_ + lane];
            k1 += ed * Wk[d * DA_ + lane + 64];
        }
        s_q[e][lane]      = q0 * inv_sqrt_da;
        s_q[e][lane + 64] = q1 * inv_sqrt_da;
        s_k[e][lane]      = k0;
        s_k[e][lane + 64] = k1;
    }
    __syncthreads();

    // ---------- energy[i][j] = q[i] . k[j] ----------
    #pragma unroll
    for (int rep = 0; rep < 4; ++rep) {
        const int idx = rep * 64 + lane;
        const int i = idx >> 4, j = idx & 15;
        float acc = 0.f;
        #pragma unroll 8
        for (int d = 0; d < DA_; ++d)
            acc += s_q[i][d] * s_k[j][d];
        s_en[i][j] = acc;
    }
    __syncthreads();

    // ---------- softmax over query axis i (per column j), then mean over j ----------
    if (lane < E_) {
        const int j = lane;
        float M = -1e30f;
        #pragma unroll
        for (int i = 0; i < E_; ++i) M = fmaxf(M, s_en[i][j]);
        float Ssum = 0.f;
        #pragma unroll
        for (int i = 0; i < E_; ++i) Ssum += __expf(s_en[i][j] - M);
        s_colM[j] = M;
        s_colS[j] = Ssum;
    }
    __syncthreads();
    if (lane < E_) {
        const int e = lane;
        float acc = 0.f;
        #pragma unroll
        for (int j = 0; j < E_; ++j)
            acc += __expf(s_en[e][j] - s_colM[j]) / s_colS[j];
        s_amean[e] = acc * (1.f / 16.f);
    }
    __syncthreads();

    // ---------- attn_out[d] = sum_e ent[e][d] * amean[e] ----------
    {
        float acc = 0.f;
        #pragma unroll
        for (int e = 0; e < E_; ++e) acc += s_ent[e][lane] * s_amean[e];
        s_aout[lane] = acc;
    }
    __syncthreads();

    // ---------- wf layer 1: h[t] = relu(aout @ wf_W1 + wf_b1), t = lane ----------
    {
        float acc = wf_b1[lane];
        #pragma unroll 8
        for (int d = 0; d < D_; ++d) acc += s_aout[d] * wf_W1[d * H_ + lane];
        s_h[lane] = fmaxf(acc, 0.f);
    }
    __syncthreads();

    // ---------- wf layer 2, hyper bias b1, v net : lanes < 32 ----------
    float wf_m = 0.f, b1_m = 0.f, hv_m = 0.f;
    if (lane < M_) {
        const int m = lane;
        float acc = wf_b2[m];
        #pragma unroll 8
        for (int t = 0; t < H_; ++t) acc += s_h[t] * wf_W2[t * M_ + m];
        wf_m = fabsf(acc);

        float accb = hb_b[m];
        #pragma unroll 8
        for (int d = 0; d < D_; ++d) accb += s_aout[d] * hb_W[d * M_ + m];
        b1_m = accb;

        float accv = v_b1[m];
        #pragma unroll 8
        for (int d = 0; d < D_; ++d) accv += s_aout[d] * v_W1[d * M_ + m];
        hv_m = fmaxf(accv, 0.f) * v_W2[m];   // v_W2 is [32,1]
    }
    __syncthreads();  // s_h reused below

    // ---------- per-agent hyper w1 + mixing accumulate ----------
    float hidden_pre = 0.f;   // valid in lanes < 32
    const float* qs = agent_qs + (size_t)site * A_;
    for (int a = 0; a < A_; ++a) {
        float acc = w1_b1[lane];
        #pragma unroll 8
        for (int c = 0; c < D_; ++c) acc += s_aout[c]   * w1_W1[c * H_ + lane];
        #pragma unroll 8
        for (int c = 0; c < D_; ++c) acc += s_ent[a][c] * w1_W1[(D_ + c) * H_ + lane];
        s_h[lane] = fmaxf(acc, 0.f);
        __syncthreads();
        if (lane < M_) {
            float acc2 = w1_b2[lane];
            #pragma unroll 8
            for (int t = 0; t < H_; ++t) acc2 += s_h[t] * w1_W2[t * M_ + lane];
            hidden_pre += qs[a] * fabsf(acc2);
        }
        __syncthreads();
    }

    // ---------- elu, dot with wf, add v, reduce ----------
    float contrib = 0.f;
    if (lane < M_) {
        float hid = hidden_pre + b1_m;
        hid = (hid > 0.f) ? hid : (__expf(hid) - 1.f);   // elu(alpha=1), e^x
        contrib = hid * wf_m + hv_m;
    }
    s_red[lane] = contrib;
    __syncthreads();
    if (lane == 0) {
        float t = v_b2[0];
        #pragma unroll
        for (int i = 0; i < 64; ++i) t += s_red[i];
        out[site] = t;
    }
}

extern "C" void kernel_launch(void* const* d_in, const int* in_sizes, int n_in,
                              void* d_out, int out_size, void* d_ws, size_t ws_size,
                              hipStream_t stream) {
    const float* p[25];
    for (int i = 0; i < 25; ++i) p[i] = (const float*)d_in[i];
    qmix_fwd<<<B_ * S_, 64, 0, stream>>>(
        p[0], p[1], p[2], p[3], p[4], p[5], p[6], p[7], p[8], p[9], p[10],
        p[11], p[12], p[13], p[14], p[15], p[16], p[17], p[18], p[19], p[20],
        p[21], p[22], p[23], p[24],
        (float*)d_out);
}

// Round 4
// 297.406 us; speedup vs baseline: 3.4144x; 3.4144x over previous
//
#include <hip/hip_runtime.h>
#include <hip/hip_bf16.h>

// QMixer forward, MI355X gfx950. fp32 in/out.
// B=128 S=128 A=8 En=8 E=16 NFal=32 NFen=16 D=64 Da=128 M=32 H=64.
// Key algebra: softmax over query axis i makes per-column-j additive terms
// cancel ->  energy[i][j] ~ e_i (Wq Wk^T / sqrt(Da)) e_j^T + e_i.(Wq bk)/sqrt(Da).
// Precompute Mt[d][c] = (Wq Wk^T)[c][d]/s and vq = Wq bk / s into d_ws.

#define B_   128
#define S_   128
#define BS_  (B_ * S_)
#define A_   8
#define EN_  8
#define E_   16
#define D_   64
#define DA_  128
#define M_   32
#define H_   64
#define NFAL 32
#define NFEN 16

#define INV_S 0.08838834764831845f  // 1/sqrt(128)

// ---------------- precompute: Mt (transposed, [d][c]) and vq ----------------
__global__ __launch_bounds__(64)
void qmix_pre(const float* __restrict__ Wq, const float* __restrict__ Wk,
              const float* __restrict__ bk, float* __restrict__ Mt,
              float* __restrict__ vq)
{
    const int d = blockIdx.x;    // 0..63  (e_j dimension)
    const int c = threadIdx.x;   // 0..63  (e_i dimension)
    float acc = 0.f;
    #pragma unroll 8
    for (int t = 0; t < DA_; ++t)
        acc += Wq[c * DA_ + t] * Wk[d * DA_ + t];   // Wk row uniform -> s_load
    Mt[d * 64 + c] = acc * INV_S;

    // vq[d] = (Wq bk)[d] / s  -- wave reduction
    float p = Wq[d * DA_ + c] * bk[c] + Wq[d * DA_ + 64 + c] * bk[64 + c];
    #pragma unroll
    for (int off = 32; off >= 1; off >>= 1)
        p += __shfl_down(p, off, 64);
    if (c == 0) vq[d] = p * INV_S;
}

// ---------------- main: one 64-lane wave per (b,s) site ----------------
__global__ __launch_bounds__(64)
void qmix_main(const float* __restrict__ agent_qs,
               const float* __restrict__ ally,  const float* __restrict__ enemy,
               const float* __restrict__ W_al,  const float* __restrict__ b_al,
               const float* __restrict__ W_en,  const float* __restrict__ b_en,
               const float* __restrict__ w1_W1, const float* __restrict__ w1_b1,
               const float* __restrict__ w1_W2, const float* __restrict__ w1_b2,
               const float* __restrict__ wf_W1, const float* __restrict__ wf_b1,
               const float* __restrict__ wf_W2, const float* __restrict__ wf_b2,
               const float* __restrict__ hb_W,  const float* __restrict__ hb_b,
               const float* __restrict__ v_W1,  const float* __restrict__ v_b1,
               const float* __restrict__ v_W2,  const float* __restrict__ v_b2,
               const float* __restrict__ Mt,    const float* __restrict__ vq,
               float* __restrict__ out)
{
    const int site = blockIdx.x;
    const int lane = threadIdx.x;

    __shared__ float s_fal[8][32];        // ally features
    __shared__ float s_fen[8][16];        // enemy features
    __shared__ float s_ent[E_][68];       // embeddings; pad 68: 16B-aligned rows, odd/4 banks
    __shared__ float s_t[E_][68];         // t = ent @ M (scaled); reused as s_hall[8][64]
    __shared__ float s_en[E_][E_ + 1];    // energy
    __shared__ float s_pq[E_];
    __shared__ float s_colM[E_], s_colS[E_], s_amean[E_];
    __shared__ float s_aout[64];
    __shared__ float s_h[64];
    __shared__ float s_b1[32];
    __shared__ float s_hv[32];

    // ---- stage per-site features (coalesced) ----
    #pragma unroll
    for (int it = 0; it < 4; ++it) {
        const int flat = it * 64 + lane;
        const int e = flat >> 5, c = flat & 31;
        s_fal[e][c] = ally[(size_t)e * BS_ * NFAL + (size_t)site * NFAL + c];
    }
    #pragma unroll
    for (int it = 0; it < 2; ++it) {
        const int flat = it * 64 + lane;
        const int e = flat >> 4, c = flat & 15;
        s_fen[e][c] = enemy[(size_t)e * BS_ * NFEN + (size_t)site * NFEN + c];
    }
    __syncthreads();

    // ---- entity encoders (weights outermost: 8-way entity reuse) ----
    {
        float acc[8];
        const float bal = b_al[lane];
        #pragma unroll
        for (int e = 0; e < 8; ++e) acc[e] = bal;
        #pragma unroll 2
        for (int c4 = 0; c4 < 8; ++c4) {
            const int r = c4 * 4;
            const float w0 = W_al[(r + 0) * D_ + lane];
            const float w1v = W_al[(r + 1) * D_ + lane];
            const float w2 = W_al[(r + 2) * D_ + lane];
            const float w3 = W_al[(r + 3) * D_ + lane];
            #pragma unroll
            for (int e = 0; e < 8; ++e) {
                const float4 f = *(const float4*)&s_fal[e][r];
                acc[e] += f.x * w0 + f.y * w1v + f.z * w2 + f.w * w3;
            }
        }
        #pragma unroll
        for (int e = 0; e < 8; ++e) s_ent[e][lane] = acc[e];
    }
    {
        float acc[8];
        const float ben = b_en[lane];
        #pragma unroll
        for (int e = 0; e < 8; ++e) acc[e] = ben;
        #pragma unroll 2
        for (int c4 = 0; c4 < 4; ++c4) {
            const int r = c4 * 4;
            const float w0 = W_en[(r + 0) * D_ + lane];
            const float w1v = W_en[(r + 1) * D_ + lane];
            const float w2 = W_en[(r + 2) * D_ + lane];
            const float w3 = W_en[(r + 3) * D_ + lane];
            #pragma unroll
            for (int e = 0; e < 8; ++e) {
                const float4 f = *(const float4*)&s_fen[e][r];
                acc[e] += f.x * w0 + f.y * w1v + f.z * w2 + f.w * w3;
            }
        }
        #pragma unroll
        for (int e = 0; e < 8; ++e) s_ent[8 + e][lane] = acc[e];
    }
    __syncthreads();

    // ---- pq_i = e_i . vq  (lanes < 16; vq uniform -> scalar loads) ----
    if (lane < E_) {
        float p = 0.f;
        #pragma unroll 4
        for (int d4 = 0; d4 < 16; ++d4) {
            const float4 ev = *(const float4*)&s_ent[lane][d4 * 4];
            const float4 vv = *(const float4*)&vq[d4 * 4];
            p += ev.x * vv.x + ev.y * vv.y + ev.z * vv.z + ev.w * vv.w;
        }
        s_pq[lane] = p;
    }

    // ---- t[e][d] = sum_c ent[e][c] * M[c][d]   (lane = d) ----
    {
        float tacc[E_];
        #pragma unroll
        for (int e = 0; e < E_; ++e) tacc[e] = 0.f;
        #pragma unroll 4
        for (int c4 = 0; c4 < 16; ++c4) {
            const float4 mv = *(const float4*)&Mt[lane * 64 + c4 * 4];
            #pragma unroll
            for (int e = 0; e < E_; ++e) {
                const float4 av = *(const float4*)&s_ent[e][c4 * 4];
                tacc[e] += av.x * mv.x + av.y * mv.y + av.z * mv.z + av.w * mv.w;
            }
        }
        #pragma unroll
        for (int e = 0; e < E_; ++e) s_t[e][lane] = tacc[e];
    }
    __syncthreads();

    // ---- energy[i][j] = t_i . e_j + pq_i ----
    #pragma unroll
    for (int rep = 0; rep < 4; ++rep) {
        const int i = rep * 4 + (lane >> 4);
        const int j = lane & 15;
        float a = s_pq[i];
        #pragma unroll 4
        for (int d4 = 0; d4 < 16; ++d4) {
            const float4 tv = *(const float4*)&s_t[i][d4 * 4];
            const float4 ev = *(const float4*)&s_ent[j][d4 * 4];
            a += tv.x * ev.x + tv.y * ev.y + tv.z * ev.z + tv.w * ev.w;
        }
        s_en[i][j] = a;
    }
    __syncthreads();

    // ---- softmax over i (per column j), then mean over j ----
    if (lane < E_) {
        const int j = lane;
        float mx = -3.4e38f;
        #pragma unroll
        for (int i = 0; i < E_; ++i) mx = fmaxf(mx, s_en[i][j]);
        float ss = 0.f;
        #pragma unroll
        for (int i = 0; i < E_; ++i) ss += __expf(s_en[i][j] - mx);
        s_colM[j] = mx;
        s_colS[j] = 1.f / ss;
    }
    __syncthreads();
    if (lane < E_) {
        const int e = lane;
        float am = 0.f;
        #pragma unroll
        for (int j = 0; j < E_; ++j)
            am += __expf(s_en[e][j] - s_colM[j]) * s_colS[j];
        s_amean[e] = am * (1.f / 16.f);
    }
    __syncthreads();

    // ---- attn_out[d] = sum_e ent[e][d] * amean[e] ----
    {
        float a = 0.f;
        #pragma unroll
        for (int e = 0; e < E_; ++e) a += s_ent[e][lane] * s_amean[e];
        s_aout[lane] = a;
    }
    __syncthreads();

    // ---- fused: wf layer1 (all lanes), w1 base (all lanes), hb | v_l1 (half lanes) ----
    const float* Wx = (lane < M_) ? (hb_W + lane) : (v_W1 + (lane - M_));
    float acc_wf = wf_b1[lane];
    float base   = w1_b1[lane];
    float acc_x  = (lane < M_) ? hb_b[lane] : v_b1[lane - M_];
    #pragma unroll 4
    for (int d4 = 0; d4 < 16; ++d4) {
        const int r = d4 * 4;
        const float4 av = *(const float4*)&s_aout[r];
        acc_wf += av.x * wf_W1[(r + 0) * H_ + lane] + av.y * wf_W1[(r + 1) * H_ + lane]
                + av.z * wf_W1[(r + 2) * H_ + lane] + av.w * wf_W1[(r + 3) * H_ + lane];
        base   += av.x * w1_W1[(r + 0) * H_ + lane] + av.y * w1_W1[(r + 1) * H_ + lane]
                + av.z * w1_W1[(r + 2) * H_ + lane] + av.w * w1_W1[(r + 3) * H_ + lane];
        acc_x  += av.x * Wx[(r + 0) * M_] + av.y * Wx[(r + 1) * M_]
                + av.z * Wx[(r + 2) * M_] + av.w * Wx[(r + 3) * M_];
    }
    s_h[lane] = fmaxf(acc_wf, 0.f);
    if (lane < M_) s_b1[lane] = acc_x;                                  // hyper bias b1
    else           s_hv[lane - M_] = fmaxf(acc_x, 0.f) * v_W2[lane - M_]; // v partial
    __syncthreads();

    // ---- wf layer2 (lanes < 32) ----
    float wfm = 0.f;
    if (lane < M_) {
        float a2 = wf_b2[lane];
        #pragma unroll 4
        for (int t4 = 0; t4 < 16; ++t4) {
            const int r = t4 * 4;
            const float4 h4 = *(const float4*)&s_h[r];
            a2 += h4.x * wf_W2[(r + 0) * M_ + lane] + h4.y * wf_W2[(r + 1) * M_ + lane]
                + h4.z * wf_W2[(r + 2) * M_ + lane] + h4.w * wf_W2[(r + 3) * M_ + lane];
        }
        wfm = fabsf(a2);
    }

    // ---- agent hyper w1 layer1 for all 8 agents (weights reused 8x) ----
    float* s_hall = &s_t[0][0];   // alias: s_t dead after energy; [8][64] stride 64
    {
        float acc[A_];
        #pragma unroll
        for (int a = 0; a < A_; ++a) acc[a] = base;
        #pragma unroll 2
        for (int c4 = 0; c4 < 16; ++c4) {
            const int r = D_ + c4 * 4;   // ally-embed half of w1_W1
            const float w0 = w1_W1[(r + 0) * H_ + lane];
            const float w1v = w1_W1[(r + 1) * H_ + lane];
            const float w2 = w1_W1[(r + 2) * H_ + lane];
            const float w3 = w1_W1[(r + 3) * H_ + lane];
            #pragma unroll
            for (int a = 0; a < A_; ++a) {
                const float4 ev = *(const float4*)&s_ent[a][c4 * 4];
                acc[a] += ev.x * w0 + ev.y * w1v + ev.z * w2 + ev.w * w3;
            }
        }
        #pragma unroll
        for (int a = 0; a < A_; ++a) s_hall[a * 64 + lane] = fmaxf(acc[a], 0.f);
    }
    __syncthreads();

    // ---- layer2 + mixing accumulate (lanes < 32, weights reused 8x) ----
    float hidden_pre = 0.f;
    if (lane < M_) {
        float a2[A_];
        const float b2l = w1_b2[lane];
        #pragma unroll
        for (int a = 0; a < A_; ++a) a2[a] = b2l;
        #pragma unroll 2
        for (int t4 = 0; t4 < 16; ++t4) {
            const int r = t4 * 4;
            const float w0 = w1_W2[(r + 0) * M_ + lane];
            const float w1v = w1_W2[(r + 1) * M_ + lane];
            const float w2 = w1_W2[(r + 2) * M_ + lane];
            const float w3 = w1_W2[(r + 3) * M_ + lane];
            #pragma unroll
            for (int a = 0; a < A_; ++a) {
                const float4 h4 = *(const float4*)&s_hall[a * 64 + r];
                a2[a] += h4.x * w0 + h4.y * w1v + h4.z * w2 + h4.w * w3;
            }
        }
        const float* qs = agent_qs + (size_t)site * A_;
        #pragma unroll
        for (int a = 0; a < A_; ++a) hidden_pre += qs[a] * fabsf(a2[a]);
    }

    // ---- elu, mix with wf, add v, reduce over m ----
    float contrib = 0.f;
    if (lane < M_) {
        float hid = hidden_pre + s_b1[lane];
        hid = (hid > 0.f) ? hid : (__expf(hid) - 1.f);
        contrib = hid * wfm + s_hv[lane];
    }
    #pragma unroll
    for (int off = 16; off >= 1; off >>= 1)
        contrib += __shfl_down(contrib, off, 64);
    if (lane == 0) out[site] = contrib + v_b2[0];
}

extern "C" void kernel_launch(void* const* d_in, const int* in_sizes, int n_in,
                              void* d_out, int out_size, void* d_ws, size_t ws_size,
                              hipStream_t stream) {
    const float* p[25];
    for (int i = 0; i < 25; ++i) p[i] = (const float*)d_in[i];
    // d_in: 0 agent_qs, 1 ally, 2 enemy, 3 W_al, 4 b_al, 5 W_en, 6 b_en,
    //       7 Wq, 8 bq, 9 Wk, 10 bk, 11 w1_W1, 12 w1_b1, 13 w1_W2, 14 w1_b2,
    //       15 wf_W1, 16 wf_b1, 17 wf_W2, 18 wf_b2, 19 hb_W, 20 hb_b,
    //       21 v_W1, 22 v_b1, 23 v_W2, 24 v_b2
    float* Mt = (float*)d_ws;            // 64*64 floats
    float* vq = Mt + 64 * 64;            // 64 floats

    qmix_pre<<<64, 64, 0, stream>>>(p[7], p[9], p[10], Mt, vq);
    qmix_main<<<BS_, 64, 0, stream>>>(
        p[0], p[1], p[2], p[3], p[4], p[5], p[6],
        p[11], p[12], p[13], p[14], p[15], p[16], p[17], p[18],
        p[19], p[20], p[21], p[22], p[23], p[24],
        Mt, vq, (float*)d_out);
}

// Round 5
// 202.940 us; speedup vs baseline: 5.0037x; 1.4655x over previous
//
#include <hip/hip_runtime.h>
#include <hip/hip_bf16.h>

// QMixer forward, MI355X gfx950. fp32 in/out, bf16 MFMA for all matmul blocks.
// B=128 S=128 A=8 En=8 E=16 NFal=32 NFen=16 D=64 Da=128 M=32 H=64.
// Algebra (verified R4): softmax over query axis i cancels per-column-j terms:
//   energy[i][j] = e_i (Wq Wk^T/sqrt(Da)) e_j^T + e_i.(Wq bk)/sqrt(Da)
// Pre-kernel builds bf16 B-fragment tiles (MFMA-ready) for M, W_al, W_en,
// w1_W1, w1_W2 in d_ws, plus vq. Main kernel: 1 wave per (b,s) site.
// MFMA 16x16x32 layouts (HW-verified): A[m=lane&15][k=quad*8+j],
// B[k=quad*8+j][n=lane&15], C/D[row=quad*4+r][col=lane&15].

#define B_   128
#define S_   128
#define BS_  (B_ * S_)
#define INV_S 0.08838834764831845f  // 1/sqrt(128)

typedef short bs8 __attribute__((ext_vector_type(8)));
typedef float f4  __attribute__((ext_vector_type(4)));

#define MFMA(a, b, c) __builtin_amdgcn_mfma_f32_16x16x32_bf16((a), (b), (c), 0, 0, 0)
#define LOADB(t) (*(const bs8*)&fb[(size_t)(t) * 512 + lane * 8])

__device__ __forceinline__ short f2bf(float f) {
    union { float f; unsigned u; } v; v.f = f;
    unsigned r = v.u + 0x7fffu + ((v.u >> 16) & 1u);   // RNE
    return (short)(r >> 16);
}

// ---------------- pre-kernel: weight fragments + vq ----------------
// frag tile = 512 bf16: [lane][j], elem j = W[k = ks*32+quad*8+j][n = n0+l16]
// tiles: 0-7 M(ks*4+n0t) | 8-11 W_al | 12-15 W_en(K=16 zero-pad) |
//        16-31 w1_W1(ks*4+n0t) | 32-35 w1_W2(ks*2+n0t)
__global__ __launch_bounds__(64)
void qmix_pre(const float* __restrict__ Wq, const float* __restrict__ Wk,
              const float* __restrict__ bk,
              const float* __restrict__ W_al, const float* __restrict__ W_en,
              const float* __restrict__ w1_W1, const float* __restrict__ w1_W2,
              short* __restrict__ fb, float* __restrict__ vq)
{
    const int blk = blockIdx.x, lane = threadIdx.x;
    const int quad = lane >> 4, l16 = lane & 15;
    if (blk < 8) {
        // M[k][n] = dot(Wq[k,:], Wk[n,:]) * INV_S
        const int ks = blk >> 2, n = (blk & 3) * 16 + l16;
        bs8 v;
        #pragma unroll
        for (int j = 0; j < 8; ++j) {
            const int k = ks * 32 + quad * 8 + j;
            float acc = 0.f;
            for (int t = 0; t < 128; ++t)
                acc += Wq[k * 128 + t] * Wk[n * 128 + t];
            v[j] = f2bf(acc * INV_S);
        }
        *(bs8*)&fb[(size_t)blk * 512 + lane * 8] = v;
    } else if (blk < 16) {
        const bool en = (blk >= 12);
        const float* W = en ? W_en : W_al;
        const int Krows = en ? 16 : 32;
        const int n = ((blk - (en ? 12 : 8)) & 3) * 16 + l16;
        bs8 v;
        #pragma unroll
        for (int j = 0; j < 8; ++j) {
            const int k = quad * 8 + j;
            v[j] = (k < Krows) ? f2bf(W[k * 64 + n]) : (short)0;
        }
        *(bs8*)&fb[(size_t)blk * 512 + lane * 8] = v;
    } else if (blk < 32) {
        const int t = blk - 16, ks = t >> 2, n = (t & 3) * 16 + l16;
        bs8 v;
        #pragma unroll
        for (int j = 0; j < 8; ++j)
            v[j] = f2bf(w1_W1[(ks * 32 + quad * 8 + j) * 64 + n]);
        *(bs8*)&fb[(size_t)blk * 512 + lane * 8] = v;
    } else if (blk < 36) {
        const int t = blk - 32, ks = t >> 1, n = (t & 1) * 16 + l16;
        bs8 v;
        #pragma unroll
        for (int j = 0; j < 8; ++j)
            v[j] = f2bf(w1_W2[(ks * 32 + quad * 8 + j) * 32 + n]);
        *(bs8*)&fb[(size_t)blk * 512 + lane * 8] = v;
    } else {
        float acc = 0.f;
        for (int t = 0; t < 128; ++t) acc += Wq[lane * 128 + t] * bk[t];
        vq[lane] = acc * INV_S;
    }
}

// ---------------- main: one 64-lane wave per site ----------------
__global__ __launch_bounds__(64)
void qmix_main(const float* __restrict__ agent_qs,
               const float* __restrict__ ally, const float* __restrict__ enemy,
               const float* __restrict__ b_al, const float* __restrict__ b_en,
               const float* __restrict__ w1_b1, const float* __restrict__ w1_b2,
               const float* __restrict__ wf_W1, const float* __restrict__ wf_b1,
               const float* __restrict__ wf_W2, const float* __restrict__ wf_b2,
               const float* __restrict__ hb_W,  const float* __restrict__ hb_b,
               const float* __restrict__ v_W1,  const float* __restrict__ v_b1,
               const float* __restrict__ v_W2,  const float* __restrict__ v_b2,
               const short* __restrict__ fb,    const float* __restrict__ vq,
               float* __restrict__ out)
{
    const int site = blockIdx.x;
    const int lane = threadIdx.x, quad = lane >> 4, l16 = lane & 15;

    __shared__ short s_entb[16][72];   // bf16 embeds; row 144B: 16B-aligned, 2-way banks
    __shared__ float s_entf[16][68];   // fp32 embeds (epilogue precision)
    __shared__ short s_scr[16][72];    // t (bf16) then hall (bf16)
    __shared__ float s_en[16][17];
    __shared__ float s_aoutf[64];
    __shared__ short s_aoutb[64];
    __shared__ float s_h[64];
    __shared__ float s_red[4][32];
    __shared__ float s_pq[16], s_colM[16], s_colS[16], s_amean[16];
    __shared__ float s_qs[8], s_b1[32], s_hv[32];

    if (lane < 8) s_qs[lane] = agent_qs[(size_t)site * 8 + lane];

    // ---- encoder A-frags: ally rows 0-7, enemy rows 8-15 (others exact zero) ----
    bs8 a_al = {0,0,0,0,0,0,0,0}, a_en = {0,0,0,0,0,0,0,0};
    if (l16 < 8) {
        const float* pa = ally + ((size_t)l16 * BS_ + site) * 32 + quad * 8;
        const float4 f0 = *(const float4*)pa, f1 = *(const float4*)(pa + 4);
        a_al[0]=f2bf(f0.x); a_al[1]=f2bf(f0.y); a_al[2]=f2bf(f0.z); a_al[3]=f2bf(f0.w);
        a_al[4]=f2bf(f1.x); a_al[5]=f2bf(f1.y); a_al[6]=f2bf(f1.z); a_al[7]=f2bf(f1.w);
    } else if (quad < 2) {   // enemy K=16: quads 0,1 only
        const float* pe = enemy + ((size_t)(l16 - 8) * BS_ + site) * 16 + quad * 8;
        const float4 f0 = *(const float4*)pe, f1 = *(const float4*)(pe + 4);
        a_en[0]=f2bf(f0.x); a_en[1]=f2bf(f0.y); a_en[2]=f2bf(f0.z); a_en[3]=f2bf(f0.w);
        a_en[4]=f2bf(f1.x); a_en[5]=f2bf(f1.y); a_en[6]=f2bf(f1.z); a_en[7]=f2bf(f1.w);
    }

    // ---- encoders: D rows 0-7 = ally@W_al, rows 8-15 = enemy@W_en ----
    #pragma unroll
    for (int n0t = 0; n0t < 4; ++n0t) {
        f4 acc = {0.f, 0.f, 0.f, 0.f};
        acc = MFMA(a_al, LOADB(8 + n0t), acc);
        acc = MFMA(a_en, LOADB(12 + n0t), acc);
        const int d = n0t * 16 + l16;
        const float bal = b_al[d], ben = b_en[d];
        #pragma unroll
        for (int r = 0; r < 4; ++r) {
            const int row = quad * 4 + r;
            const float v = acc[r] + (row < 8 ? bal : ben);
            s_entf[row][d] = v;
            s_entb[row][d] = f2bf(v);
        }
    }
    __syncthreads();

    // ---- t = ent @ M  (A = ent rows, reused as energy B below) ----
    const bs8 ae0 = *(const bs8*)&s_entb[l16][quad * 8];
    const bs8 ae1 = *(const bs8*)&s_entb[l16][32 + quad * 8];
    f4 tacc[4];
    #pragma unroll
    for (int n0t = 0; n0t < 4; ++n0t) {
        f4 acc = {0.f, 0.f, 0.f, 0.f};
        acc = MFMA(ae0, LOADB(0 + n0t), acc);
        acc = MFMA(ae1, LOADB(4 + n0t), acc);
        tacc[n0t] = acc;
    }
    // pq_i = e_i . vq  (VALU, lanes<16)
    if (lane < 16) {
        float p = 0.f;
        #pragma unroll 8
        for (int d = 0; d < 64; ++d) p += s_entf[lane][d] * vq[d];
        s_pq[lane] = p;
    }
    #pragma unroll
    for (int n0t = 0; n0t < 4; ++n0t) {
        const int d = n0t * 16 + l16;
        #pragma unroll
        for (int r = 0; r < 4; ++r) s_scr[quad * 4 + r][d] = f2bf(tacc[n0t][r]);
    }
    __syncthreads();

    // ---- energy = t @ ent^T + pq ----
    {
        const bs8 at0 = *(const bs8*)&s_scr[l16][quad * 8];
        const bs8 at1 = *(const bs8*)&s_scr[l16][32 + quad * 8];
        f4 eacc = {0.f, 0.f, 0.f, 0.f};
        eacc = MFMA(at0, ae0, eacc);
        eacc = MFMA(at1, ae1, eacc);
        #pragma unroll
        for (int r = 0; r < 4; ++r)
            s_en[quad * 4 + r][l16] = eacc[r] + s_pq[quad * 4 + r];
    }
    __syncthreads();

    // ---- softmax over i per column j, then mean over j ----
    if (lane < 16) {
        const int j = lane;
        float mx = -3.4e38f;
        #pragma unroll
        for (int i = 0; i < 16; ++i) mx = fmaxf(mx, s_en[i][j]);
        float ss = 0.f;
        #pragma unroll
        for (int i = 0; i < 16; ++i) ss += __expf(s_en[i][j] - mx);
        s_colM[j] = mx;
        s_colS[j] = 1.f / ss;
    }
    __syncthreads();
    if (lane < 16) {
        float am = 0.f;
        #pragma unroll
        for (int j = 0; j < 16; ++j)
            am += __expf(s_en[lane][j] - s_colM[j]) * s_colS[j];
        s_amean[lane] = am * (1.f / 16.f);
    }
    __syncthreads();

    // ---- attn_out ----
    {
        float ao = 0.f;
        #pragma unroll
        for (int e = 0; e < 16; ++e) ao += s_entf[e][lane] * s_amean[e];
        s_aoutf[lane] = ao;
        s_aoutb[lane] = f2bf(ao);
    }
    __syncthreads();

    // ---- VALU: wf layer1 (all lanes) + hb | v_l1 (lane halves) ----
    {
        const float* Wx = (lane < 32) ? (hb_W + lane) : (v_W1 + (lane - 32));
        float acc_wf = wf_b1[lane];
        float acc_x  = (lane < 32) ? hb_b[lane] : v_b1[lane - 32];
        #pragma unroll 4
        for (int d4 = 0; d4 < 16; ++d4) {
            const int r = d4 * 4;
            const float4 av = *(const float4*)&s_aoutf[r];
            acc_wf += av.x * wf_W1[(r + 0) * 64 + lane] + av.y * wf_W1[(r + 1) * 64 + lane]
                    + av.z * wf_W1[(r + 2) * 64 + lane] + av.w * wf_W1[(r + 3) * 64 + lane];
            acc_x  += av.x * Wx[(r + 0) * 32] + av.y * Wx[(r + 1) * 32]
                    + av.z * Wx[(r + 2) * 32] + av.w * Wx[(r + 3) * 32];
        }
        s_h[lane] = fmaxf(acc_wf, 0.f);
        if (lane < 32) s_b1[lane] = acc_x;
        else           s_hv[lane - 32] = fmaxf(acc_x, 0.f) * v_W2[lane - 32];
    }
    __syncthreads();

    // ---- wf layer2 (lanes<32) ----
    float wfm = 0.f;
    if (lane < 32) {
        float a2 = wf_b2[lane];
        #pragma unroll 4
        for (int t4 = 0; t4 < 16; ++t4) {
            const int r = t4 * 4;
            const float4 h4 = *(const float4*)&s_h[r];
            a2 += h4.x * wf_W2[(r + 0) * 32 + lane] + h4.y * wf_W2[(r + 1) * 32 + lane]
                + h4.z * wf_W2[(r + 2) * 32 + lane] + h4.w * wf_W2[(r + 3) * 32 + lane];
        }
        wfm = fabsf(a2);
    }

    // ---- agent hypernet L1: emi[16x128] @ w1_W1[128x64] (rows 0-7 = agents) ----
    {
        const bs8 a0 = *(const bs8*)&s_aoutb[quad * 8];        // k 0..31: aout (bcast)
        const bs8 a1 = *(const bs8*)&s_aoutb[32 + quad * 8];   // k 32..63
        const bs8 a2 = *(const bs8*)&s_entb[l16][quad * 8];    // k 64..95: ent_a
        const bs8 a3 = *(const bs8*)&s_entb[l16][32 + quad * 8];
        f4 hacc[4];
        #pragma unroll
        for (int n0t = 0; n0t < 4; ++n0t) {
            f4 acc = {0.f, 0.f, 0.f, 0.f};
            acc = MFMA(a0, LOADB(16 + 0 + n0t), acc);
            acc = MFMA(a1, LOADB(16 + 4 + n0t), acc);
            acc = MFMA(a2, LOADB(16 + 8 + n0t), acc);
            acc = MFMA(a3, LOADB(16 + 12 + n0t), acc);
            hacc[n0t] = acc;
        }
        __syncthreads();   // s_scr reuse: t-reads long done
        #pragma unroll
        for (int n0t = 0; n0t < 4; ++n0t) {
            const int d = n0t * 16 + l16;
            const float b1v = w1_b1[d];
            #pragma unroll
            for (int r = 0; r < 4; ++r) {
                const int row = quad * 4 + r;
                if (row < 8)
                    s_scr[row][d] = f2bf(fmaxf(hacc[n0t][r] + b1v, 0.f));
            }
        }
    }
    __syncthreads();

    // ---- agent hypernet L2 + mixing partials ----
    {
        const bs8 ah0 = *(const bs8*)&s_scr[l16][quad * 8];
        const bs8 ah1 = *(const bs8*)&s_scr[l16][32 + quad * 8];
        #pragma unroll
        for (int n0t = 0; n0t < 2; ++n0t) {
            f4 acc = {0.f, 0.f, 0.f, 0.f};
            acc = MFMA(ah0, LOADB(32 + 0 + n0t), acc);
            acc = MFMA(ah1, LOADB(32 + 2 + n0t), acc);
            const int col = n0t * 16 + l16;
            const float b2v = w1_b2[col];
            float p = 0.f;
            if (quad < 2) {       // rows 0-7 = agents; guard keeps NaN-garbage out
                #pragma unroll
                for (int r = 0; r < 4; ++r)
                    p += s_qs[quad * 4 + r] * fabsf(acc[r] + b2v);
            }
            s_red[quad][col] = p;
        }
    }
    __syncthreads();

    // ---- elu, mix, reduce ----
    float contrib = 0.f;
    if (lane < 32) {
        float hp = s_red[0][lane] + s_red[1][lane] + s_red[2][lane] + s_red[3][lane]
                 + s_b1[lane];
        hp = (hp > 0.f) ? hp : (__expf(hp) - 1.f);
        contrib = hp * wfm + s_hv[lane];
    }
    #pragma unroll
    for (int off = 16; off >= 1; off >>= 1)
        contrib += __shfl_down(contrib, off, 64);
    if (lane == 0) out[site] = contrib + v_b2[0];
}

extern "C" void kernel_launch(void* const* d_in, const int* in_sizes, int n_in,
                              void* d_out, int out_size, void* d_ws, size_t ws_size,
                              hipStream_t stream) {
    const float* p[25];
    for (int i = 0; i < 25; ++i) p[i] = (const float*)d_in[i];
    // 0 agent_qs 1 ally 2 enemy 3 W_al 4 b_al 5 W_en 6 b_en 7 Wq 8 bq 9 Wk 10 bk
    // 11 w1_W1 12 w1_b1 13 w1_W2 14 w1_b2 15 wf_W1 16 wf_b1 17 wf_W2 18 wf_b2
    // 19 hb_W 20 hb_b 21 v_W1 22 v_b1 23 v_W2 24 v_b2
    short* fb = (short*)d_ws;                          // 36 tiles * 512 bf16 = 72 KB
    float* vq = (float*)((char*)d_ws + 36 * 512 * 2);  // 64 floats

    qmix_pre<<<37, 64, 0, stream>>>(p[7], p[9], p[10], p[3], p[5], p[11], p[13],
                                    fb, vq);
    qmix_main<<<BS_, 64, 0, stream>>>(
        p[0], p[1], p[2], p[4], p[6], p[12], p[14],
        p[15], p[16], p[17], p[18], p[19], p[20], p[21], p[22], p[23], p[24],
        fb, vq, (float*)d_out);
}

// Round 6
// 186.110 us; speedup vs baseline: 5.4562x; 1.0904x over previous
//
#include <hip/hip_runtime.h>
#include <hip/hip_bf16.h>

// QMixer forward, MI355X gfx950. fp32 in/out, bf16 MFMA for all matmul blocks.
// B=128 S=128 A=8 En=8 E=16 NFal=32 NFen=16 D=64 Da=128 M=32 H=64.
// Algebra (verified R4): softmax over query axis i cancels per-column-j terms:
//   energy[i][j] = e_i (Wq Wk^T/sqrt(Da)) e_j^T + e_i.(Wq bk)/sqrt(Da)
// R6: precompute split into qmix_pre1 (one wave per M element / vq element,
// massively parallel) + qmix_pack (trivial frag reformat). Main kernel is the
// R5-verified one, unchanged (absmax 3.9e-3).
// MFMA 16x16x32 layouts (HW-verified): A[m=lane&15][k=quad*8+j],
// B[k=quad*8+j][n=lane&15], C/D[row=quad*4+r][col=lane&15].

#define B_   128
#define S_   128
#define BS_  (B_ * S_)
#define INV_S 0.08838834764831845f  // 1/sqrt(128)

typedef short bs8 __attribute__((ext_vector_type(8)));
typedef float f4  __attribute__((ext_vector_type(4)));

#define MFMA(a, b, c) __builtin_amdgcn_mfma_f32_16x16x32_bf16((a), (b), (c), 0, 0, 0)
#define LOADB(t) (*(const bs8*)&fb[(size_t)(t) * 512 + lane * 8])

__device__ __forceinline__ short f2bf(float f) {
    union { float f; unsigned u; } v; v.f = f;
    unsigned r = v.u + 0x7fffu + ((v.u >> 16) & 1u);   // RNE
    return (short)(r >> 16);
}

// ---------------- pre1: M (one wave per element) and vq ----------------
__global__ __launch_bounds__(64)
void qmix_pre1(const float* __restrict__ Wq, const float* __restrict__ Wk,
               const float* __restrict__ bk,
               float* __restrict__ Ms, float* __restrict__ vq)
{
    const int blk = blockIdx.x, t = threadIdx.x;
    float p;
    if (blk < 4096) {
        const int k = blk >> 6, n = blk & 63;
        p = Wq[k * 128 + t] * Wk[n * 128 + t]
          + Wq[k * 128 + 64 + t] * Wk[n * 128 + 64 + t];
        #pragma unroll
        for (int off = 32; off >= 1; off >>= 1) p += __shfl_down(p, off, 64);
        if (t == 0) Ms[k * 64 + n] = p * INV_S;
    } else {
        const int d = blk - 4096;
        p = Wq[d * 128 + t] * bk[t] + Wq[d * 128 + 64 + t] * bk[64 + t];
        #pragma unroll
        for (int off = 32; off >= 1; off >>= 1) p += __shfl_down(p, off, 64);
        if (t == 0) vq[d] = p * INV_S;
    }
}

// ---------------- pack: bf16 B-fragment tiles ----------------
// frag tile = 512 bf16: [lane][j], elem j = W[k = ks*32+quad*8+j][n = n0+l16]
// tiles: 0-7 M(ks*4+n0t) | 8-11 W_al | 12-15 W_en(K=16 zero-pad) |
//        16-31 w1_W1(ks*4+n0t) | 32-35 w1_W2(ks*2+n0t)
__global__ __launch_bounds__(64)
void qmix_pack(const float* __restrict__ Ms,
               const float* __restrict__ W_al, const float* __restrict__ W_en,
               const float* __restrict__ w1_W1, const float* __restrict__ w1_W2,
               short* __restrict__ fb)
{
    const int blk = blockIdx.x, lane = threadIdx.x;
    const int quad = lane >> 4, l16 = lane & 15;
    bs8 v;
    if (blk < 8) {
        const int ks = blk >> 2, n = (blk & 3) * 16 + l16;
        #pragma unroll
        for (int j = 0; j < 8; ++j)
            v[j] = f2bf(Ms[(ks * 32 + quad * 8 + j) * 64 + n]);
    } else if (blk < 16) {
        const bool en = (blk >= 12);
        const float* W = en ? W_en : W_al;
        const int Krows = en ? 16 : 32;
        const int n = ((blk - (en ? 12 : 8)) & 3) * 16 + l16;
        #pragma unroll
        for (int j = 0; j < 8; ++j) {
            const int k = quad * 8 + j;
            v[j] = (k < Krows) ? f2bf(W[k * 64 + n]) : (short)0;
        }
    } else if (blk < 32) {
        const int t = blk - 16, ks = t >> 2, n = (t & 3) * 16 + l16;
        #pragma unroll
        for (int j = 0; j < 8; ++j)
            v[j] = f2bf(w1_W1[(ks * 32 + quad * 8 + j) * 64 + n]);
    } else {
        const int t = blk - 32, ks = t >> 1, n = (t & 1) * 16 + l16;
        #pragma unroll
        for (int j = 0; j < 8; ++j)
            v[j] = f2bf(w1_W2[(ks * 32 + quad * 8 + j) * 32 + n]);
    }
    *(bs8*)&fb[(size_t)blk * 512 + lane * 8] = v;
}

// ---------------- main: one 64-lane wave per site (R5-verified) ----------------
__global__ __launch_bounds__(64)
void qmix_main(const float* __restrict__ agent_qs,
               const float* __restrict__ ally, const float* __restrict__ enemy,
               const float* __restrict__ b_al, const float* __restrict__ b_en,
               const float* __restrict__ w1_b1, const float* __restrict__ w1_b2,
               const float* __restrict__ wf_W1, const float* __restrict__ wf_b1,
               const float* __restrict__ wf_W2, const float* __restrict__ wf_b2,
               const float* __restrict__ hb_W,  const float* __restrict__ hb_b,
               const float* __restrict__ v_W1,  const float* __restrict__ v_b1,
               const float* __restrict__ v_W2,  const float* __restrict__ v_b2,
               const short* __restrict__ fb,    const float* __restrict__ vq,
               float* __restrict__ out)
{
    const int site = blockIdx.x;
    const int lane = threadIdx.x, quad = lane >> 4, l16 = lane & 15;

    __shared__ short s_entb[16][72];   // bf16 embeds; row 144B: 16B-aligned, 2-way banks
    __shared__ float s_entf[16][68];   // fp32 embeds (epilogue precision)
    __shared__ short s_scr[16][72];    // t (bf16) then hall (bf16)
    __shared__ float s_en[16][17];
    __shared__ float s_aoutf[64];
    __shared__ short s_aoutb[64];
    __shared__ float s_h[64];
    __shared__ float s_red[4][32];
    __shared__ float s_pq[16], s_colM[16], s_colS[16], s_amean[16];
    __shared__ float s_qs[8], s_b1[32], s_hv[32];

    if (lane < 8) s_qs[lane] = agent_qs[(size_t)site * 8 + lane];

    // ---- encoder A-frags: ally rows 0-7, enemy rows 8-15 (others exact zero) ----
    bs8 a_al = {0,0,0,0,0,0,0,0}, a_en = {0,0,0,0,0,0,0,0};
    if (l16 < 8) {
        const float* pa = ally + ((size_t)l16 * BS_ + site) * 32 + quad * 8;
        const float4 f0 = *(const float4*)pa, f1 = *(const float4*)(pa + 4);
        a_al[0]=f2bf(f0.x); a_al[1]=f2bf(f0.y); a_al[2]=f2bf(f0.z); a_al[3]=f2bf(f0.w);
        a_al[4]=f2bf(f1.x); a_al[5]=f2bf(f1.y); a_al[6]=f2bf(f1.z); a_al[7]=f2bf(f1.w);
    } else if (quad < 2) {   // enemy K=16: quads 0,1 only
        const float* pe = enemy + ((size_t)(l16 - 8) * BS_ + site) * 16 + quad * 8;
        const float4 f0 = *(const float4*)pe, f1 = *(const float4*)(pe + 4);
        a_en[0]=f2bf(f0.x); a_en[1]=f2bf(f0.y); a_en[2]=f2bf(f0.z); a_en[3]=f2bf(f0.w);
        a_en[4]=f2bf(f1.x); a_en[5]=f2bf(f1.y); a_en[6]=f2bf(f1.z); a_en[7]=f2bf(f1.w);
    }

    // ---- encoders: D rows 0-7 = ally@W_al, rows 8-15 = enemy@W_en ----
    #pragma unroll
    for (int n0t = 0; n0t < 4; ++n0t) {
        f4 acc = {0.f, 0.f, 0.f, 0.f};
        acc = MFMA(a_al, LOADB(8 + n0t), acc);
        acc = MFMA(a_en, LOADB(12 + n0t), acc);
        const int d = n0t * 16 + l16;
        const float bal = b_al[d], ben = b_en[d];
        #pragma unroll
        for (int r = 0; r < 4; ++r) {
            const int row = quad * 4 + r;
            const float v = acc[r] + (row < 8 ? bal : ben);
            s_entf[row][d] = v;
            s_entb[row][d] = f2bf(v);
        }
    }
    __syncthreads();

    // ---- t = ent @ M  (A = ent rows, reused as energy B below) ----
    const bs8 ae0 = *(const bs8*)&s_entb[l16][quad * 8];
    const bs8 ae1 = *(const bs8*)&s_entb[l16][32 + quad * 8];
    f4 tacc[4];
    #pragma unroll
    for (int n0t = 0; n0t < 4; ++n0t) {
        f4 acc = {0.f, 0.f, 0.f, 0.f};
        acc = MFMA(ae0, LOADB(0 + n0t), acc);
        acc = MFMA(ae1, LOADB(4 + n0t), acc);
        tacc[n0t] = acc;
    }
    // pq_i = e_i . vq  (VALU, lanes<16)
    if (lane < 16) {
        float p = 0.f;
        #pragma unroll 8
        for (int d = 0; d < 64; ++d) p += s_entf[lane][d] * vq[d];
        s_pq[lane] = p;
    }
    #pragma unroll
    for (int n0t = 0; n0t < 4; ++n0t) {
        const int d = n0t * 16 + l16;
        #pragma unroll
        for (int r = 0; r < 4; ++r) s_scr[quad * 4 + r][d] = f2bf(tacc[n0t][r]);
    }
    __syncthreads();

    // ---- energy = t @ ent^T + pq ----
    {
        const bs8 at0 = *(const bs8*)&s_scr[l16][quad * 8];
        const bs8 at1 = *(const bs8*)&s_scr[l16][32 + quad * 8];
        f4 eacc = {0.f, 0.f, 0.f, 0.f};
        eacc = MFMA(at0, ae0, eacc);
        eacc = MFMA(at1, ae1, eacc);
        #pragma unroll
        for (int r = 0; r < 4; ++r)
            s_en[quad * 4 + r][l16] = eacc[r] + s_pq[quad * 4 + r];
    }
    __syncthreads();

    // ---- softmax over i per column j, then mean over j ----
    if (lane < 16) {
        const int j = lane;
        float mx = -3.4e38f;
        #pragma unroll
        for (int i = 0; i < 16; ++i) mx = fmaxf(mx, s_en[i][j]);
        float ss = 0.f;
        #pragma unroll
        for (int i = 0; i < 16; ++i) ss += __expf(s_en[i][j] - mx);
        s_colM[j] = mx;
        s_colS[j] = 1.f / ss;
    }
    __syncthreads();
    if (lane < 16) {
        float am = 0.f;
        #pragma unroll
        for (int j = 0; j < 16; ++j)
            am += __expf(s_en[lane][j] - s_colM[j]) * s_colS[j];
        s_amean[lane] = am * (1.f / 16.f);
    }
    __syncthreads();

    // ---- attn_out ----
    {
        float ao = 0.f;
        #pragma unroll
        for (int e = 0; e < 16; ++e) ao += s_entf[e][lane] * s_amean[e];
        s_aoutf[lane] = ao;
        s_aoutb[lane] = f2bf(ao);
    }
    __syncthreads();

    // ---- VALU: wf layer1 (all lanes) + hb | v_l1 (lane halves) ----
    {
        const float* Wx = (lane < 32) ? (hb_W + lane) : (v_W1 + (lane - 32));
        float acc_wf = wf_b1[lane];
        float acc_x  = (lane < 32) ? hb_b[lane] : v_b1[lane - 32];
        #pragma unroll 4
        for (int d4 = 0; d4 < 16; ++d4) {
            const int r = d4 * 4;
            const float4 av = *(const float4*)&s_aoutf[r];
            acc_wf += av.x * wf_W1[(r + 0) * 64 + lane] + av.y * wf_W1[(r + 1) * 64 + lane]
                    + av.z * wf_W1[(r + 2) * 64 + lane] + av.w * wf_W1[(r + 3) * 64 + lane];
            acc_x  += av.x * Wx[(r + 0) * 32] + av.y * Wx[(r + 1) * 32]
                    + av.z * Wx[(r + 2) * 32] + av.w * Wx[(r + 3) * 32];
        }
        s_h[lane] = fmaxf(acc_wf, 0.f);
        if (lane < 32) s_b1[lane] = acc_x;
        else           s_hv[lane - 32] = fmaxf(acc_x, 0.f) * v_W2[lane - 32];
    }
    __syncthreads();

    // ---- wf layer2 (lanes<32) ----
    float wfm = 0.f;
    if (lane < 32) {
        float a2 = wf_b2[lane];
        #pragma unroll 4
        for (int t4 = 0; t4 < 16; ++t4) {
            const int r = t4 * 4;
            const float4 h4 = *(const float4*)&s_h[r];
            a2 += h4.x * wf_W2[(r + 0) * 32 + lane] + h4.y * wf_W2[(r + 1) * 32 + lane]
                + h4.z * wf_W2[(r + 2) * 32 + lane] + h4.w * wf_W2[(r + 3) * 32 + lane];
        }
        wfm = fabsf(a2);
    }

    // ---- agent hypernet L1: emi[16x128] @ w1_W1[128x64] (rows 0-7 = agents) ----
    {
        const bs8 a0 = *(const bs8*)&s_aoutb[quad * 8];        // k 0..31: aout (bcast)
        const bs8 a1 = *(const bs8*)&s_aoutb[32 + quad * 8];   // k 32..63
        const bs8 a2 = *(const bs8*)&s_entb[l16][quad * 8];    // k 64..95: ent_a
        const bs8 a3 = *(const bs8*)&s_entb[l16][32 + quad * 8];
        f4 hacc[4];
        #pragma unroll
        for (int n0t = 0; n0t < 4; ++n0t) {
            f4 acc = {0.f, 0.f, 0.f, 0.f};
            acc = MFMA(a0, LOADB(16 + 0 + n0t), acc);
            acc = MFMA(a1, LOADB(16 + 4 + n0t), acc);
            acc = MFMA(a2, LOADB(16 + 8 + n0t), acc);
            acc = MFMA(a3, LOADB(16 + 12 + n0t), acc);
            hacc[n0t] = acc;
        }
        __syncthreads();   // s_scr reuse: t-reads long done
        #pragma unroll
        for (int n0t = 0; n0t < 4; ++n0t) {
            const int d = n0t * 16 + l16;
            const float b1v = w1_b1[d];
            #pragma unroll
            for (int r = 0; r < 4; ++r) {
                const int row = quad * 4 + r;
                if (row < 8)
                    s_scr[row][d] = f2bf(fmaxf(hacc[n0t][r] + b1v, 0.f));
            }
        }
    }
    __syncthreads();

    // ---- agent hypernet L2 + mixing partials ----
    {
        const bs8 ah0 = *(const bs8*)&s_scr[l16][quad * 8];
        const bs8 ah1 = *(const bs8*)&s_scr[l16][32 + quad * 8];
        #pragma unroll
        for (int n0t = 0; n0t < 2; ++n0t) {
            f4 acc = {0.f, 0.f, 0.f, 0.f};
            acc = MFMA(ah0, LOADB(32 + 0 + n0t), acc);
            acc = MFMA(ah1, LOADB(32 + 2 + n0t), acc);
            const int col = n0t * 16 + l16;
            const float b2v = w1_b2[col];
            float p = 0.f;
            if (quad < 2) {       // rows 0-7 = agents; guard keeps NaN-garbage out
                #pragma unroll
                for (int r = 0; r < 4; ++r)
                    p += s_qs[quad * 4 + r] * fabsf(acc[r] + b2v);
            }
            s_red[quad][col] = p;
        }
    }
    __syncthreads();

    // ---- elu, mix, reduce ----
    float contrib = 0.f;
    if (lane < 32) {
        float hp = s_red[0][lane] + s_red[1][lane] + s_red[2][lane] + s_red[3][lane]
                 + s_b1[lane];
        hp = (hp > 0.f) ? hp : (__expf(hp) - 1.f);
        contrib = hp * wfm + s_hv[lane];
    }
    #pragma unroll
    for (int off = 16; off >= 1; off >>= 1)
        contrib += __shfl_down(contrib, off, 64);
    if (lane == 0) out[site] = contrib + v_b2[0];
}

extern "C" void kernel_launch(void* const* d_in, const int* in_sizes, int n_in,
                              void* d_out, int out_size, void* d_ws, size_t ws_size,
                              hipStream_t stream) {
    const float* p[25];
    for (int i = 0; i < 25; ++i) p[i] = (const float*)d_in[i];
    // 0 agent_qs 1 ally 2 enemy 3 W_al 4 b_al 5 W_en 6 b_en 7 Wq 8 bq 9 Wk 10 bk
    // 11 w1_W1 12 w1_b1 13 w1_W2 14 w1_b2 15 wf_W1 16 wf_b1 17 wf_W2 18 wf_b2
    // 19 hb_W 20 hb_b 21 v_W1 22 v_b1 23 v_W2 24 v_b2
    short* fb = (short*)d_ws;                           // 36 tiles * 512 bf16 = 73728 B
    float* vq = (float*)((char*)d_ws + 36 * 512 * 2);   // 64 floats
    float* Ms = vq + 64;                                // 64*64 floats

    qmix_pre1<<<4096 + 64, 64, 0, stream>>>(p[7], p[9], p[10], Ms, vq);
    qmix_pack<<<36, 64, 0, stream>>>(Ms, p[3], p[5], p[11], p[13], fb);
    qmix_main<<<BS_, 64, 0, stream>>>(
        p[0], p[1], p[2], p[4], p[6], p[12], p[14],
        p[15], p[16], p[17], p[18], p[19], p[20], p[21], p[22], p[23], p[24],
        fb, vq, (float*)d_out);
}

// Round 7
// 174.902 us; speedup vs baseline: 5.8059x; 1.0641x over previous
//
#include <hip/hip_runtime.h>
#include <hip/hip_bf16.h>

// QMixer forward, MI355X gfx950. fp32 in/out, bf16 MFMA for all matmul blocks.
// B=128 S=128 A=8 En=8 E=16 NFal=32 NFen=16 D=64 Da=128 M=32 H=64.
// Algebra (verified R4): softmax over query axis i cancels per-column-j terms:
//   energy[i][j] = e_i (Wq Wk^T/sqrt(Da)) e_j^T + e_i.(Wq bk)/sqrt(Da)
// R7: softmax/attn_out fully registerized (shuffle reductions, fp32 encoder
// accs kept in regs); pq via 2 extra MFMAs on vq-column tiles; LDS 11.8->6.1KB.
// MFMA 16x16x32 layouts (HW-verified): A[m=lane&15][k=quad*8+j],
// B[k=quad*8+j][n=lane&15], C/D[row=quad*4+r][col=lane&15].

#define B_   128
#define S_   128
#define BS_  (B_ * S_)
#define INV_S 0.08838834764831845f  // 1/sqrt(128)

typedef short bs8 __attribute__((ext_vector_type(8)));
typedef float f4  __attribute__((ext_vector_type(4)));

#define MFMA(a, b, c) __builtin_amdgcn_mfma_f32_16x16x32_bf16((a), (b), (c), 0, 0, 0)
#define LOADB(t) (*(const bs8*)&fb[(size_t)(t) * 512 + lane * 8])

__device__ __forceinline__ short f2bf(float f) {
    union { float f; unsigned u; } v; v.f = f;
    unsigned r = v.u + 0x7fffu + ((v.u >> 16) & 1u);   // RNE
    return (short)(r >> 16);
}

// ---------------- pre1: M (one wave per element) and vq ----------------
__global__ __launch_bounds__(64)
void qmix_pre1(const float* __restrict__ Wq, const float* __restrict__ Wk,
               const float* __restrict__ bk,
               float* __restrict__ Ms, float* __restrict__ vq)
{
    const int blk = blockIdx.x, t = threadIdx.x;
    float p;
    if (blk < 4096) {
        const int k = blk >> 6, n = blk & 63;
        p = Wq[k * 128 + t] * Wk[n * 128 + t]
          + Wq[k * 128 + 64 + t] * Wk[n * 128 + 64 + t];
        #pragma unroll
        for (int off = 32; off >= 1; off >>= 1) p += __shfl_down(p, off, 64);
        if (t == 0) Ms[k * 64 + n] = p * INV_S;
    } else {
        const int d = blk - 4096;
        p = Wq[d * 128 + t] * bk[t] + Wq[d * 128 + 64 + t] * bk[64 + t];
        #pragma unroll
        for (int off = 32; off >= 1; off >>= 1) p += __shfl_down(p, off, 64);
        if (t == 0) vq[d] = p * INV_S;
    }
}

// ---------------- pack: bf16 B-fragment tiles ----------------
// frag tile = 512 bf16: [lane][j], elem j = W[k = ks*32+quad*8+j][n = n0+l16]
// tiles: 0-7 M(ks*4+n0t) | 8-11 W_al | 12-15 W_en(K=16 zero-pad) |
//        16-31 w1_W1(ks*4+n0t) | 32-35 w1_W2(ks*2+n0t) | 36-37 vq column
__global__ __launch_bounds__(64)
void qmix_pack(const float* __restrict__ Ms,
               const float* __restrict__ W_al, const float* __restrict__ W_en,
               const float* __restrict__ w1_W1, const float* __restrict__ w1_W2,
               const float* __restrict__ vq,
               short* __restrict__ fb)
{
    const int blk = blockIdx.x, lane = threadIdx.x;
    const int quad = lane >> 4, l16 = lane & 15;
    bs8 v;
    if (blk < 8) {
        const int ks = blk >> 2, n = (blk & 3) * 16 + l16;
        #pragma unroll
        for (int j = 0; j < 8; ++j)
            v[j] = f2bf(Ms[(ks * 32 + quad * 8 + j) * 64 + n]);
    } else if (blk < 16) {
        const bool en = (blk >= 12);
        const float* W = en ? W_en : W_al;
        const int Krows = en ? 16 : 32;
        const int n = ((blk - (en ? 12 : 8)) & 3) * 16 + l16;
        #pragma unroll
        for (int j = 0; j < 8; ++j) {
            const int k = quad * 8 + j;
            v[j] = (k < Krows) ? f2bf(W[k * 64 + n]) : (short)0;
        }
    } else if (blk < 32) {
        const int t = blk - 16, ks = t >> 2, n = (t & 3) * 16 + l16;
        #pragma unroll
        for (int j = 0; j < 8; ++j)
            v[j] = f2bf(w1_W1[(ks * 32 + quad * 8 + j) * 64 + n]);
    } else if (blk < 36) {
        const int t = blk - 32, ks = t >> 1, n = (t & 1) * 16 + l16;
        #pragma unroll
        for (int j = 0; j < 8; ++j)
            v[j] = f2bf(w1_W2[(ks * 32 + quad * 8 + j) * 32 + n]);
    } else {                        // 36,37: B[k][0] = vq[ks*32+k], other cols 0
        const int ks = blk - 36;
        #pragma unroll
        for (int j = 0; j < 8; ++j)
            v[j] = (l16 == 0) ? f2bf(vq[ks * 32 + quad * 8 + j]) : (short)0;
    }
    *(bs8*)&fb[(size_t)blk * 512 + lane * 8] = v;
}

// ---------------- main: one 64-lane wave per site ----------------
__global__ __launch_bounds__(64)
void qmix_main(const float* __restrict__ agent_qs,
               const float* __restrict__ ally, const float* __restrict__ enemy,
               const float* __restrict__ b_al, const float* __restrict__ b_en,
               const float* __restrict__ w1_b1, const float* __restrict__ w1_b2,
               const float* __restrict__ wf_W1, const float* __restrict__ wf_b1,
               const float* __restrict__ wf_W2, const float* __restrict__ wf_b2,
               const float* __restrict__ hb_W,  const float* __restrict__ hb_b,
               const float* __restrict__ v_W1,  const float* __restrict__ v_b1,
               const float* __restrict__ v_W2,  const float* __restrict__ v_b2,
               const short* __restrict__ fb,
               float* __restrict__ out)
{
    const int site = blockIdx.x;
    const int lane = threadIdx.x, quad = lane >> 4, l16 = lane & 15;

    __shared__ __align__(16) short s_entb[16][72];  // bf16 embeds (144B rows)
    __shared__ __align__(16) short s_scr[16][72];   // t (bf16), then hall (bf16)
    __shared__ __align__(16) float s_aoutf[64];
    __shared__ __align__(16) short s_aoutb[64];
    __shared__ __align__(16) float s_h[64];
    __shared__ __align__(16) float s_red[4][32];
    __shared__ float s_b1[32], s_hv[32], s_qs[8];

    if (lane < 8) s_qs[lane] = agent_qs[(size_t)site * 8 + lane];

    // ---- encoder A-frags: ally rows 0-7, enemy rows 8-15 (others exact zero) ----
    bs8 a_al = {0,0,0,0,0,0,0,0}, a_en = {0,0,0,0,0,0,0,0};
    if (l16 < 8) {
        const float* pa = ally + ((size_t)l16 * BS_ + site) * 32 + quad * 8;
        const float4 f0 = *(const float4*)pa, f1 = *(const float4*)(pa + 4);
        a_al[0]=f2bf(f0.x); a_al[1]=f2bf(f0.y); a_al[2]=f2bf(f0.z); a_al[3]=f2bf(f0.w);
        a_al[4]=f2bf(f1.x); a_al[5]=f2bf(f1.y); a_al[6]=f2bf(f1.z); a_al[7]=f2bf(f1.w);
    } else if (quad < 2) {   // enemy K=16: quads 0,1 only
        const float* pe = enemy + ((size_t)(l16 - 8) * BS_ + site) * 16 + quad * 8;
        const float4 f0 = *(const float4*)pe, f1 = *(const float4*)(pe + 4);
        a_en[0]=f2bf(f0.x); a_en[1]=f2bf(f0.y); a_en[2]=f2bf(f0.z); a_en[3]=f2bf(f0.w);
        a_en[4]=f2bf(f1.x); a_en[5]=f2bf(f1.y); a_en[6]=f2bf(f1.z); a_en[7]=f2bf(f1.w);
    }

    // ---- encoders: D rows 0-7 = ally@W_al, rows 8-15 = enemy@W_en ----
    // Keep fp32 accs in regs (encf) for the attn_out epilogue.
    f4 encf[4];
    #pragma unroll
    for (int n0t = 0; n0t < 4; ++n0t) {
        f4 acc = {0.f, 0.f, 0.f, 0.f};
        acc = MFMA(a_al, LOADB(8 + n0t), acc);
        acc = MFMA(a_en, LOADB(12 + n0t), acc);
        const int d = n0t * 16 + l16;
        const float bal = b_al[d], ben = b_en[d];
        #pragma unroll
        for (int r = 0; r < 4; ++r) {
            const int row = quad * 4 + r;
            const float v = acc[r] + (row < 8 ? bal : ben);
            encf[n0t][r] = v;
            s_entb[row][d] = f2bf(v);
        }
    }
    __syncthreads();

    // ---- t = ent @ M ; pq = ent @ vq (MFMA, col-0 tiles) ----
    const bs8 ae0 = *(const bs8*)&s_entb[l16][quad * 8];
    const bs8 ae1 = *(const bs8*)&s_entb[l16][32 + quad * 8];
    f4 pqacc = {0.f, 0.f, 0.f, 0.f};
    pqacc = MFMA(ae0, LOADB(36), pqacc);
    pqacc = MFMA(ae1, LOADB(37), pqacc);
    #pragma unroll
    for (int n0t = 0; n0t < 4; ++n0t) {
        f4 acc = {0.f, 0.f, 0.f, 0.f};
        acc = MFMA(ae0, LOADB(0 + n0t), acc);
        acc = MFMA(ae1, LOADB(4 + n0t), acc);
        const int d = n0t * 16 + l16;
        #pragma unroll
        for (int r = 0; r < 4; ++r) s_scr[quad * 4 + r][d] = f2bf(acc[r]);
    }
    __syncthreads();

    // ---- energy = t @ ent^T + pq  (rows quad*4+r, col l16; pq bcast via shfl) ----
    f4 eacc = {0.f, 0.f, 0.f, 0.f};
    {
        const bs8 at0 = *(const bs8*)&s_scr[l16][quad * 8];
        const bs8 at1 = *(const bs8*)&s_scr[l16][32 + quad * 8];
        eacc = MFMA(at0, ae0, eacc);
        eacc = MFMA(at1, ae1, eacc);
        const int src = lane & 48;   // l16==0 lane of this quad holds pq[row]
        #pragma unroll
        for (int r = 0; r < 4; ++r) eacc[r] += __shfl(pqacc[r], src, 64);
    }

    // ---- softmax over rows i (per col j=l16), in registers ----
    float amean_r[4];
    {
        float cmax = fmaxf(fmaxf(eacc[0], eacc[1]), fmaxf(eacc[2], eacc[3]));
        cmax = fmaxf(cmax, __shfl_xor(cmax, 16, 64));
        cmax = fmaxf(cmax, __shfl_xor(cmax, 32, 64));
        float er[4], csum = 0.f;
        #pragma unroll
        for (int r = 0; r < 4; ++r) { er[r] = __expf(eacc[r] - cmax); csum += er[r]; }
        csum += __shfl_xor(csum, 16, 64);
        csum += __shfl_xor(csum, 32, 64);
        const float inv = 1.f / csum;
        #pragma unroll
        for (int r = 0; r < 4; ++r) {
            float p = er[r] * inv;              // attn[row][col]
            p += __shfl_xor(p, 1, 64);          // row-mean over cols (l16 butterfly)
            p += __shfl_xor(p, 2, 64);
            p += __shfl_xor(p, 4, 64);
            p += __shfl_xor(p, 8, 64);
            amean_r[r] = p * (1.f / 16.f);
        }
    }

    // ---- attn_out in regs: aout[n0t*16+l16] = sum_rows amean*encf, quad-reduced ----
    #pragma unroll
    for (int n0t = 0; n0t < 4; ++n0t) {
        float ap = amean_r[0] * encf[n0t][0] + amean_r[1] * encf[n0t][1]
                 + amean_r[2] * encf[n0t][2] + amean_r[3] * encf[n0t][3];
        ap += __shfl_xor(ap, 16, 64);
        ap += __shfl_xor(ap, 32, 64);
        if (quad == 0) {
            s_aoutf[n0t * 16 + l16] = ap;
            s_aoutb[n0t * 16 + l16] = f2bf(ap);
        }
    }
    __syncthreads();

    // ---- VALU: wf layer1 (all lanes) + hb | v_l1 (lane halves) ----
    {
        const float* Wx = (lane < 32) ? (hb_W + lane) : (v_W1 + (lane - 32));
        float acc_wf = wf_b1[lane];
        float acc_x  = (lane < 32) ? hb_b[lane] : v_b1[lane - 32];
        #pragma unroll 4
        for (int d4 = 0; d4 < 16; ++d4) {
            const int r = d4 * 4;
            const float4 av = *(const float4*)&s_aoutf[r];
            acc_wf += av.x * wf_W1[(r + 0) * 64 + lane] + av.y * wf_W1[(r + 1) * 64 + lane]
                    + av.z * wf_W1[(r + 2) * 64 + lane] + av.w * wf_W1[(r + 3) * 64 + lane];
            acc_x  += av.x * Wx[(r + 0) * 32] + av.y * Wx[(r + 1) * 32]
                    + av.z * Wx[(r + 2) * 32] + av.w * Wx[(r + 3) * 32];
        }
        s_h[lane] = fmaxf(acc_wf, 0.f);
        if (lane < 32) s_b1[lane] = acc_x;
        else           s_hv[lane - 32] = fmaxf(acc_x, 0.f) * v_W2[lane - 32];
    }
    __syncthreads();

    // ---- wf layer2 (lanes<32) ----
    float wfm = 0.f;
    if (lane < 32) {
        float a2 = wf_b2[lane];
        #pragma unroll 4
        for (int t4 = 0; t4 < 16; ++t4) {
            const int r = t4 * 4;
            const float4 h4 = *(const float4*)&s_h[r];
            a2 += h4.x * wf_W2[(r + 0) * 32 + lane] + h4.y * wf_W2[(r + 1) * 32 + lane]
                + h4.z * wf_W2[(r + 2) * 32 + lane] + h4.w * wf_W2[(r + 3) * 32 + lane];
        }
        wfm = fabsf(a2);
    }

    // ---- agent hypernet L1: emi[16x128] @ w1_W1[128x64] (rows 0-7 = agents) ----
    {
        const bs8 a0 = *(const bs8*)&s_aoutb[quad * 8];        // k 0..31: aout (bcast)
        const bs8 a1 = *(const bs8*)&s_aoutb[32 + quad * 8];   // k 32..63
        // k 64..127: ally embed = ae0/ae1 still live in regs
        f4 hacc[4];
        #pragma unroll
        for (int n0t = 0; n0t < 4; ++n0t) {
            f4 acc = {0.f, 0.f, 0.f, 0.f};
            acc = MFMA(a0,  LOADB(16 + 0 + n0t), acc);
            acc = MFMA(a1,  LOADB(16 + 4 + n0t), acc);
            acc = MFMA(ae0, LOADB(16 + 8 + n0t), acc);
            acc = MFMA(ae1, LOADB(16 + 12 + n0t), acc);
            hacc[n0t] = acc;
        }
        #pragma unroll
        for (int n0t = 0; n0t < 4; ++n0t) {
            const int d = n0t * 16 + l16;
            const float b1v = w1_b1[d];
            #pragma unroll
            for (int r = 0; r < 4; ++r) {
                const int row = quad * 4 + r;
                if (row < 8)
                    s_scr[row][d] = f2bf(fmaxf(hacc[n0t][r] + b1v, 0.f));
            }
        }
    }
    __syncthreads();

    // ---- agent hypernet L2 + mixing partials ----
    {
        const bs8 ah0 = *(const bs8*)&s_scr[l16][quad * 8];
        const bs8 ah1 = *(const bs8*)&s_scr[l16][32 + quad * 8];
        #pragma unroll
        for (int n0t = 0; n0t < 2; ++n0t) {
            f4 acc = {0.f, 0.f, 0.f, 0.f};
            acc = MFMA(ah0, LOADB(32 + 0 + n0t), acc);
            acc = MFMA(ah1, LOADB(32 + 2 + n0t), acc);
            const int col = n0t * 16 + l16;
            const float b2v = w1_b2[col];
            float p = 0.f;
            if (quad < 2) {       // rows 0-7 = agents; rows 8-15 stale (discard)
                #pragma unroll
                for (int r = 0; r < 4; ++r)
                    p += s_qs[quad * 4 + r] * fabsf(acc[r] + b2v);
            }
            s_red[quad][col] = p;
        }
    }
    __syncthreads();

    // ---- elu, mix, reduce ----
    float contrib = 0.f;
    if (lane < 32) {
        float hp = s_red[0][lane] + s_red[1][lane] + s_red[2][lane] + s_red[3][lane]
                 + s_b1[lane];
        hp = (hp > 0.f) ? hp : (__expf(hp) - 1.f);
        contrib = hp * wfm + s_hv[lane];
    }
    #pragma unroll
    for (int off = 16; off >= 1; off >>= 1)
        contrib += __shfl_down(contrib, off, 64);
    if (lane == 0) out[site] = contrib + v_b2[0];
}

extern "C" void kernel_launch(void* const* d_in, const int* in_sizes, int n_in,
                              void* d_out, int out_size, void* d_ws, size_t ws_size,
                              hipStream_t stream) {
    const float* p[25];
    for (int i = 0; i < 25; ++i) p[i] = (const float*)d_in[i];
    // 0 agent_qs 1 ally 2 enemy 3 W_al 4 b_al 5 W_en 6 b_en 7 Wq 8 bq 9 Wk 10 bk
    // 11 w1_W1 12 w1_b1 13 w1_W2 14 w1_b2 15 wf_W1 16 wf_b1 17 wf_W2 18 wf_b2
    // 19 hb_W 20 hb_b 21 v_W1 22 v_b1 23 v_W2 24 v_b2
    short* fb = (short*)d_ws;                           // 38 tiles * 512 bf16
    float* vq = (float*)((char*)d_ws + 38 * 512 * 2);   // 64 floats
    float* Ms = vq + 64;                                // 64*64 floats

    qmix_pre1<<<4096 + 64, 64, 0, stream>>>(p[7], p[9], p[10], Ms, vq);
    qmix_pack<<<38, 64, 0, stream>>>(Ms, p[3], p[5], p[11], p[13], vq, fb);
    qmix_main<<<BS_, 64, 0, stream>>>(
        p[0], p[1], p[2], p[4], p[6], p[12], p[14],
        p[15], p[16], p[17], p[18], p[19], p[20], p[21], p[22], p[23], p[24],
        fb, (float*)d_out);
}

// Round 8
// 172.966 us; speedup vs baseline: 5.8708x; 1.0112x over previous
//
#include <hip/hip_runtime.h>
#include <hip/hip_bf16.h>

// QMixer forward, MI355X gfx950. fp32 in/out, bf16 MFMA for all matmul blocks.
// B=128 S=128 A=8 En=8 E=16 NFal=32 NFen=16 D=64 Da=128 M=32 H=64.
// Algebra (verified R4): softmax over query axis i cancels per-column-j terms:
//   energy[i][j] = e_i (Wq Wk^T/sqrt(Da)) e_j^T + e_i.(Wq bk)/sqrt(Da)
// R8: 2 sites per 128-thread block (1 site/wave, per-wave LDS partition) to
// beat the 16-workgroup/CU cap (R7 ceiling: 16 waves/CU). s_red/s_hv/s_b1
// replaced by shuffles; 5 barriers. ~10.6 KB LDS/block -> ~30 waves/CU static.
// MFMA 16x16x32 layouts (HW-verified): A[m=lane&15][k=quad*8+j],
// B[k=quad*8+j][n=lane&15], C/D[row=quad*4+r][col=lane&15].

#define B_   128
#define S_   128
#define BS_  (B_ * S_)
#define WPB  2
#define INV_S 0.08838834764831845f  // 1/sqrt(128)

typedef short bs8 __attribute__((ext_vector_type(8)));
typedef float f4  __attribute__((ext_vector_type(4)));

#define MFMA(a, b, c) __builtin_amdgcn_mfma_f32_16x16x32_bf16((a), (b), (c), 0, 0, 0)
#define LOADB(t) (*(const bs8*)&fb[(size_t)(t) * 512 + lane * 8])

__device__ __forceinline__ short f2bf(float f) {
    union { float f; unsigned u; } v; v.f = f;
    unsigned r = v.u + 0x7fffu + ((v.u >> 16) & 1u);   // RNE
    return (short)(r >> 16);
}

// ---------------- pre1: M (one wave per element) and vq ----------------
__global__ __launch_bounds__(64)
void qmix_pre1(const float* __restrict__ Wq, const float* __restrict__ Wk,
               const float* __restrict__ bk,
               float* __restrict__ Ms, float* __restrict__ vq)
{
    const int blk = blockIdx.x, t = threadIdx.x;
    float p;
    if (blk < 4096) {
        const int k = blk >> 6, n = blk & 63;
        p = Wq[k * 128 + t] * Wk[n * 128 + t]
          + Wq[k * 128 + 64 + t] * Wk[n * 128 + 64 + t];
        #pragma unroll
        for (int off = 32; off >= 1; off >>= 1) p += __shfl_down(p, off, 64);
        if (t == 0) Ms[k * 64 + n] = p * INV_S;
    } else {
        const int d = blk - 4096;
        p = Wq[d * 128 + t] * bk[t] + Wq[d * 128 + 64 + t] * bk[64 + t];
        #pragma unroll
        for (int off = 32; off >= 1; off >>= 1) p += __shfl_down(p, off, 64);
        if (t == 0) vq[d] = p * INV_S;
    }
}

// ---------------- pack: bf16 B-fragment tiles ----------------
// frag tile = 512 bf16: [lane][j], elem j = W[k = ks*32+quad*8+j][n = n0+l16]
// tiles: 0-7 M(ks*4+n0t) | 8-11 W_al | 12-15 W_en(K=16 zero-pad) |
//        16-31 w1_W1(ks*4+n0t) | 32-35 w1_W2(ks*2+n0t) | 36-37 vq column
__global__ __launch_bounds__(64)
void qmix_pack(const float* __restrict__ Ms,
               const float* __restrict__ W_al, const float* __restrict__ W_en,
               const float* __restrict__ w1_W1, const float* __restrict__ w1_W2,
               const float* __restrict__ vq,
               short* __restrict__ fb)
{
    const int blk = blockIdx.x, lane = threadIdx.x;
    const int quad = lane >> 4, l16 = lane & 15;
    bs8 v;
    if (blk < 8) {
        const int ks = blk >> 2, n = (blk & 3) * 16 + l16;
        #pragma unroll
        for (int j = 0; j < 8; ++j)
            v[j] = f2bf(Ms[(ks * 32 + quad * 8 + j) * 64 + n]);
    } else if (blk < 16) {
        const bool en = (blk >= 12);
        const float* W = en ? W_en : W_al;
        const int Krows = en ? 16 : 32;
        const int n = ((blk - (en ? 12 : 8)) & 3) * 16 + l16;
        #pragma unroll
        for (int j = 0; j < 8; ++j) {
            const int k = quad * 8 + j;
            v[j] = (k < Krows) ? f2bf(W[k * 64 + n]) : (short)0;
        }
    } else if (blk < 32) {
        const int t = blk - 16, ks = t >> 2, n = (t & 3) * 16 + l16;
        #pragma unroll
        for (int j = 0; j < 8; ++j)
            v[j] = f2bf(w1_W1[(ks * 32 + quad * 8 + j) * 64 + n]);
    } else if (blk < 36) {
        const int t = blk - 32, ks = t >> 1, n = (t & 1) * 16 + l16;
        #pragma unroll
        for (int j = 0; j < 8; ++j)
            v[j] = f2bf(w1_W2[(ks * 32 + quad * 8 + j) * 32 + n]);
    } else {                        // 36,37: B[k][0] = vq[ks*32+k], other cols 0
        const int ks = blk - 36;
        #pragma unroll
        for (int j = 0; j < 8; ++j)
            v[j] = (l16 == 0) ? f2bf(vq[ks * 32 + quad * 8 + j]) : (short)0;
    }
    *(bs8*)&fb[(size_t)blk * 512 + lane * 8] = v;
}

// ---------------- main: WPB sites per block, one per wave ----------------
struct __align__(16) WaveLds {
    short entb[16][72];   // bf16 embeds (144B rows: 16B-aligned, 2-way banks)
    short scr[16][72];    // t (bf16), then hall (bf16)
    float aoutf[64];
    short aoutb[64];
    float h[64];
    float qs[8];
};

__global__ __launch_bounds__(64 * WPB)
void qmix_main(const float* __restrict__ agent_qs,
               const float* __restrict__ ally, const float* __restrict__ enemy,
               const float* __restrict__ b_al, const float* __restrict__ b_en,
               const float* __restrict__ w1_b1, const float* __restrict__ w1_b2,
               const float* __restrict__ wf_W1, const float* __restrict__ wf_b1,
               const float* __restrict__ wf_W2, const float* __restrict__ wf_b2,
               const float* __restrict__ hb_W,  const float* __restrict__ hb_b,
               const float* __restrict__ v_W1,  const float* __restrict__ v_b1,
               const float* __restrict__ v_W2,  const float* __restrict__ v_b2,
               const short* __restrict__ fb,
               float* __restrict__ out)
{
    const int w    = threadIdx.x >> 6;
    const int lane = threadIdx.x & 63;
    const int site = blockIdx.x * WPB + w;
    const int quad = lane >> 4, l16 = lane & 15;

    __shared__ WaveLds lds[WPB];
    WaveLds& L = lds[w];

    if (lane < 8) L.qs[lane] = agent_qs[(size_t)site * 8 + lane];

    // ---- encoder A-frags: ally rows 0-7, enemy rows 8-15 (others exact zero) ----
    bs8 a_al = {0,0,0,0,0,0,0,0}, a_en = {0,0,0,0,0,0,0,0};
    if (l16 < 8) {
        const float* pa = ally + ((size_t)l16 * BS_ + site) * 32 + quad * 8;
        const float4 f0 = *(const float4*)pa, f1 = *(const float4*)(pa + 4);
        a_al[0]=f2bf(f0.x); a_al[1]=f2bf(f0.y); a_al[2]=f2bf(f0.z); a_al[3]=f2bf(f0.w);
        a_al[4]=f2bf(f1.x); a_al[5]=f2bf(f1.y); a_al[6]=f2bf(f1.z); a_al[7]=f2bf(f1.w);
    } else if (quad < 2) {   // enemy K=16: quads 0,1 only
        const float* pe = enemy + ((size_t)(l16 - 8) * BS_ + site) * 16 + quad * 8;
        const float4 f0 = *(const float4*)pe, f1 = *(const float4*)(pe + 4);
        a_en[0]=f2bf(f0.x); a_en[1]=f2bf(f0.y); a_en[2]=f2bf(f0.z); a_en[3]=f2bf(f0.w);
        a_en[4]=f2bf(f1.x); a_en[5]=f2bf(f1.y); a_en[6]=f2bf(f1.z); a_en[7]=f2bf(f1.w);
    }

    // ---- encoders: D rows 0-7 = ally@W_al, rows 8-15 = enemy@W_en ----
    f4 encf[4];   // fp32 embeds kept in regs for attn_out epilogue
    #pragma unroll
    for (int n0t = 0; n0t < 4; ++n0t) {
        f4 acc = {0.f, 0.f, 0.f, 0.f};
        acc = MFMA(a_al, LOADB(8 + n0t), acc);
        acc = MFMA(a_en, LOADB(12 + n0t), acc);
        const int d = n0t * 16 + l16;
        const float bal = b_al[d], ben = b_en[d];
        #pragma unroll
        for (int r = 0; r < 4; ++r) {
            const int row = quad * 4 + r;
            const float v = acc[r] + (row < 8 ? bal : ben);
            encf[n0t][r] = v;
            L.entb[row][d] = f2bf(v);
        }
    }
    __syncthreads();   // B1

    // ---- t = ent @ M ; pq = ent @ vq (MFMA, col-0 tiles) ----
    const bs8 ae0 = *(const bs8*)&L.entb[l16][quad * 8];
    const bs8 ae1 = *(const bs8*)&L.entb[l16][32 + quad * 8];
    f4 pqacc = {0.f, 0.f, 0.f, 0.f};
    pqacc = MFMA(ae0, LOADB(36), pqacc);
    pqacc = MFMA(ae1, LOADB(37), pqacc);
    #pragma unroll
    for (int n0t = 0; n0t < 4; ++n0t) {
        f4 acc = {0.f, 0.f, 0.f, 0.f};
        acc = MFMA(ae0, LOADB(0 + n0t), acc);
        acc = MFMA(ae1, LOADB(4 + n0t), acc);
        const int d = n0t * 16 + l16;
        #pragma unroll
        for (int r = 0; r < 4; ++r) L.scr[quad * 4 + r][d] = f2bf(acc[r]);
    }
    __syncthreads();   // B2

    // ---- energy = t @ ent^T + pq  (rows quad*4+r, col l16; pq bcast via shfl) ----
    f4 eacc = {0.f, 0.f, 0.f, 0.f};
    {
        const bs8 at0 = *(const bs8*)&L.scr[l16][quad * 8];
        const bs8 at1 = *(const bs8*)&L.scr[l16][32 + quad * 8];
        eacc = MFMA(at0, ae0, eacc);
        eacc = MFMA(at1, ae1, eacc);
        const int src = lane & 48;   // l16==0 lane of this quad holds pq[row]
        #pragma unroll
        for (int r = 0; r < 4; ++r) eacc[r] += __shfl(pqacc[r], src, 64);
    }

    // ---- softmax over rows i (per col j=l16), in registers ----
    float amean_r[4];
    {
        float cmax = fmaxf(fmaxf(eacc[0], eacc[1]), fmaxf(eacc[2], eacc[3]));
        cmax = fmaxf(cmax, __shfl_xor(cmax, 16, 64));
        cmax = fmaxf(cmax, __shfl_xor(cmax, 32, 64));
        float er[4], csum = 0.f;
        #pragma unroll
        for (int r = 0; r < 4; ++r) { er[r] = __expf(eacc[r] - cmax); csum += er[r]; }
        csum += __shfl_xor(csum, 16, 64);
        csum += __shfl_xor(csum, 32, 64);
        const float inv = 1.f / csum;
        #pragma unroll
        for (int r = 0; r < 4; ++r) {
            float p = er[r] * inv;              // attn[row][col]
            p += __shfl_xor(p, 1, 64);          // row-mean over cols (l16 butterfly)
            p += __shfl_xor(p, 2, 64);
            p += __shfl_xor(p, 4, 64);
            p += __shfl_xor(p, 8, 64);
            amean_r[r] = p * (1.f / 16.f);
        }
    }

    // ---- attn_out: aout[n0t*16+l16] = sum_rows amean*encf, quad-reduced ----
    #pragma unroll
    for (int n0t = 0; n0t < 4; ++n0t) {
        float ap = amean_r[0] * encf[n0t][0] + amean_r[1] * encf[n0t][1]
                 + amean_r[2] * encf[n0t][2] + amean_r[3] * encf[n0t][3];
        ap += __shfl_xor(ap, 16, 64);
        ap += __shfl_xor(ap, 32, 64);
        if (quad == 0) {
            L.aoutf[n0t * 16 + l16] = ap;
            L.aoutb[n0t * 16 + l16] = f2bf(ap);
        }
    }
    __syncthreads();   // B3

    // ---- VALU: wf layer1 (all lanes) + hb | v_l1 (lane halves) ----
    float b1m = 0.f, hvp = 0.f;
    {
        const float* Wx = (lane < 32) ? (hb_W + lane) : (v_W1 + (lane - 32));
        float acc_wf = wf_b1[lane];
        float acc_x  = (lane < 32) ? hb_b[lane] : v_b1[lane - 32];
        #pragma unroll 4
        for (int d4 = 0; d4 < 16; ++d4) {
            const int r = d4 * 4;
            const float4 av = *(const float4*)&L.aoutf[r];
            acc_wf += av.x * wf_W1[(r + 0) * 64 + lane] + av.y * wf_W1[(r + 1) * 64 + lane]
                    + av.z * wf_W1[(r + 2) * 64 + lane] + av.w * wf_W1[(r + 3) * 64 + lane];
            acc_x  += av.x * Wx[(r + 0) * 32] + av.y * Wx[(r + 1) * 32]
                    + av.z * Wx[(r + 2) * 32] + av.w * Wx[(r + 3) * 32];
        }
        L.h[lane] = fmaxf(acc_wf, 0.f);
        if (lane < 32) b1m = acc_x;                               // hyper bias b1 (reg)
        else           hvp = fmaxf(acc_x, 0.f) * v_W2[lane - 32]; // v partial
    }
    const float hvx = __shfl_xor(hvp, 32, 64);   // lanes<32 get partner's v partial
    __syncthreads();   // B4

    // ---- wf layer2 (lanes<32) ----
    float wfm = 0.f;
    if (lane < 32) {
        float a2 = wf_b2[lane];
        #pragma unroll 4
        for (int t4 = 0; t4 < 16; ++t4) {
            const int r = t4 * 4;
            const float4 h4 = *(const float4*)&L.h[r];
            a2 += h4.x * wf_W2[(r + 0) * 32 + lane] + h4.y * wf_W2[(r + 1) * 32 + lane]
                + h4.z * wf_W2[(r + 2) * 32 + lane] + h4.w * wf_W2[(r + 3) * 32 + lane];
        }
        wfm = fabsf(a2);
    }

    // ---- agent hypernet L1: emi[16x128] @ w1_W1[128x64] (rows 0-7 = agents) ----
    {
        const bs8 a0 = *(const bs8*)&L.aoutb[quad * 8];        // k 0..31: aout (bcast)
        const bs8 a1 = *(const bs8*)&L.aoutb[32 + quad * 8];   // k 32..63
        // k 64..127: ally embed = ae0/ae1 still live in regs
        f4 hacc[4];
        #pragma unroll
        for (int n0t = 0; n0t < 4; ++n0t) {
            f4 acc = {0.f, 0.f, 0.f, 0.f};
            acc = MFMA(a0,  LOADB(16 + 0 + n0t), acc);
            acc = MFMA(a1,  LOADB(16 + 4 + n0t), acc);
            acc = MFMA(ae0, LOADB(16 + 8 + n0t), acc);
            acc = MFMA(ae1, LOADB(16 + 12 + n0t), acc);
            hacc[n0t] = acc;
        }
        #pragma unroll
        for (int n0t = 0; n0t < 4; ++n0t) {
            const int d = n0t * 16 + l16;
            const float b1v = w1_b1[d];
            #pragma unroll
            for (int r = 0; r < 4; ++r) {
                const int row = quad * 4 + r;
                if (row < 8)
                    L.scr[row][d] = f2bf(fmaxf(hacc[n0t][r] + b1v, 0.f));
            }
        }
    }
    __syncthreads();   // B5

    // ---- agent hypernet L2 + mixing partials (shuffle-reduced) ----
    float p0 = 0.f, p1 = 0.f;
    {
        const bs8 ah0 = *(const bs8*)&L.scr[l16][quad * 8];
        const bs8 ah1 = *(const bs8*)&L.scr[l16][32 + quad * 8];
        #pragma unroll
        for (int n0t = 0; n0t < 2; ++n0t) {
            f4 acc = {0.f, 0.f, 0.f, 0.f};
            acc = MFMA(ah0, LOADB(32 + 0 + n0t), acc);
            acc = MFMA(ah1, LOADB(32 + 2 + n0t), acc);
            const int col = n0t * 16 + l16;
            const float b2v = w1_b2[col];
            float p = 0.f;
            if (quad < 2) {       // rows 0-7 = agents; rows 8-15 stale (discard)
                #pragma unroll
                for (int r = 0; r < 4; ++r)
                    p += L.qs[quad * 4 + r] * fabsf(acc[r] + b2v);
            }
            if (n0t == 0) p0 = p; else p1 = p;
        }
        p0 += __shfl_xor(p0, 16, 64);   // quad0+quad1 = all 8 agents (cols 0-15)
        p1 += __shfl_xor(p1, 16, 64);   // cols 16-31 (valid at quads 0,1)
    }

    // ---- elu, mix, reduce over m (lanes 0..31 hold cols 0..31) ----
    float contrib = 0.f;
    if (lane < 32) {
        float hp = (lane < 16 ? p0 : p1) + b1m;
        hp = (hp > 0.f) ? hp : (__expf(hp) - 1.f);
        contrib = hp * wfm + hvx;
    }
    #pragma unroll
    for (int off = 16; off >= 1; off >>= 1)
        contrib += __shfl_down(contrib, off, 64);
    if (lane == 0) out[site] = contrib + v_b2[0];
}

extern "C" void kernel_launch(void* const* d_in, const int* in_sizes, int n_in,
                              void* d_out, int out_size, void* d_ws, size_t ws_size,
                              hipStream_t stream) {
    const float* p[25];
    for (int i = 0; i < 25; ++i) p[i] = (const float*)d_in[i];
    // 0 agent_qs 1 ally 2 enemy 3 W_al 4 b_al 5 W_en 6 b_en 7 Wq 8 bq 9 Wk 10 bk
    // 11 w1_W1 12 w1_b1 13 w1_W2 14 w1_b2 15 wf_W1 16 wf_b1 17 wf_W2 18 wf_b2
    // 19 hb_W 20 hb_b 21 v_W1 22 v_b1 23 v_W2 24 v_b2
    short* fb = (short*)d_ws;                           // 38 tiles * 512 bf16
    float* vq = (float*)((char*)d_ws + 38 * 512 * 2);   // 64 floats
    float* Ms = vq + 64;                                // 64*64 floats

    qmix_pre1<<<4096 + 64, 64, 0, stream>>>(p[7], p[9], p[10], Ms, vq);
    qmix_pack<<<38, 64, 0, stream>>>(Ms, p[3], p[5], p[11], p[13], vq, fb);
    qmix_main<<<BS_ / WPB, 64 * WPB, 0, stream>>>(
        p[0], p[1], p[2], p[4], p[6], p[12], p[14],
        p[15], p[16], p[17], p[18], p[19], p[20], p[21], p[22], p[23], p[24],
        fb, (float*)d_out);
}

// Round 9
// 163.225 us; speedup vs baseline: 6.2212x; 1.0597x over previous
//
#include <hip/hip_runtime.h>
#include <hip/hip_bf16.h>

// QMixer forward, MI355X gfx950. fp32 in/out, bf16 MFMA for all matmul blocks.
// B=128 S=128 A=8 En=8 E=16 NFal=32 NFen=16 D=64 Da=128 M=32 H=64.
// Algebra (verified R4): softmax over query axis i cancels per-column-j terms:
//   energy[i][j] = e_i (Wq Wk^T/sqrt(Da)) e_j^T + e_i.(Wq bk)/sqrt(Da)
// R9: (1) __launch_bounds__(128,4) to lift the hidden-AGPR occupancy cap
// (R7/R8 both pinned at ~12 waves/CU); (2) wf/hb/v nets moved to MFMA with
// an all-rows-equal A-frag (lane reads wave-uniform LDS addr), killing ~190
// global dword loads + ~250 VALU FMA per wave.
// MFMA 16x16x32 layouts (HW-verified): A[m=lane&15][k=quad*8+j],
// B[k=quad*8+j][n=lane&15], C/D[row=quad*4+r][col=lane&15].

#define B_   128
#define S_   128
#define BS_  (B_ * S_)
#define WPB  2
#define INV_S 0.08838834764831845f  // 1/sqrt(128)

typedef short bs8 __attribute__((ext_vector_type(8)));
typedef float f4  __attribute__((ext_vector_type(4)));

#define MFMA(a, b, c) __builtin_amdgcn_mfma_f32_16x16x32_bf16((a), (b), (c), 0, 0, 0)
#define LOADB(t) (*(const bs8*)&fb[(size_t)(t) * 512 + lane * 8])

__device__ __forceinline__ short f2bf(float f) {
    union { float f; unsigned u; } v; v.f = f;
    unsigned r = v.u + 0x7fffu + ((v.u >> 16) & 1u);   // RNE
    return (short)(r >> 16);
}

// ---------------- pre1: M (one wave per element) and vq ----------------
__global__ __launch_bounds__(64)
void qmix_pre1(const float* __restrict__ Wq, const float* __restrict__ Wk,
               const float* __restrict__ bk,
               float* __restrict__ Ms, float* __restrict__ vq)
{
    const int blk = blockIdx.x, t = threadIdx.x;
    float p;
    if (blk < 4096) {
        const int k = blk >> 6, n = blk & 63;
        p = Wq[k * 128 + t] * Wk[n * 128 + t]
          + Wq[k * 128 + 64 + t] * Wk[n * 128 + 64 + t];
        #pragma unroll
        for (int off = 32; off >= 1; off >>= 1) p += __shfl_down(p, off, 64);
        if (t == 0) Ms[k * 64 + n] = p * INV_S;
    } else {
        const int d = blk - 4096;
        p = Wq[d * 128 + t] * bk[t] + Wq[d * 128 + 64 + t] * bk[64 + t];
        #pragma unroll
        for (int off = 32; off >= 1; off >>= 1) p += __shfl_down(p, off, 64);
        if (t == 0) vq[d] = p * INV_S;
    }
}

// ---------------- pack: bf16 B-fragment tiles ----------------
// frag tile = 512 bf16: [lane][j], elem j = W[k = ks*32+quad*8+j][n = n0+l16]
// tiles: 0-7 M(ks*4+n0t) | 8-11 W_al | 12-15 W_en(K=16 zero-pad) |
//        16-31 w1_W1(ks*4+n0t) | 32-35 w1_W2(ks*2+n0t) | 36-37 vq column |
//        38-53 bigW1=[wf_W1|hb_W|v_W1] (ks*8? -> 38+ks*8+n0t, 2ks x 8n0t) |
//        54-57 wf_W2 (54+ks*2+n0t, 2ks x 2n0t)
__global__ __launch_bounds__(64)
void qmix_pack(const float* __restrict__ Ms,
               const float* __restrict__ W_al, const float* __restrict__ W_en,
               const float* __restrict__ w1_W1, const float* __restrict__ w1_W2,
               const float* __restrict__ vq,
               const float* __restrict__ wf_W1, const float* __restrict__ hb_W,
               const float* __restrict__ v_W1,  const float* __restrict__ wf_W2,
               short* __restrict__ fb)
{
    const int blk = blockIdx.x, lane = threadIdx.x;
    const int quad = lane >> 4, l16 = lane & 15;
    bs8 v;
    if (blk < 8) {
        const int ks = blk >> 2, n = (blk & 3) * 16 + l16;
        #pragma unroll
        for (int j = 0; j < 8; ++j)
            v[j] = f2bf(Ms[(ks * 32 + quad * 8 + j) * 64 + n]);
    } else if (blk < 16) {
        const bool en = (blk >= 12);
        const float* W = en ? W_en : W_al;
        const int Krows = en ? 16 : 32;
        const int n = ((blk - (en ? 12 : 8)) & 3) * 16 + l16;
        #pragma unroll
        for (int j = 0; j < 8; ++j) {
            const int k = quad * 8 + j;
            v[j] = (k < Krows) ? f2bf(W[k * 64 + n]) : (short)0;
        }
    } else if (blk < 32) {
        const int t = blk - 16, ks = t >> 2, n = (t & 3) * 16 + l16;
        #pragma unroll
        for (int j = 0; j < 8; ++j)
            v[j] = f2bf(w1_W1[(ks * 32 + quad * 8 + j) * 64 + n]);
    } else if (blk < 36) {
        const int t = blk - 32, ks = t >> 1, n = (t & 1) * 16 + l16;
        #pragma unroll
        for (int j = 0; j < 8; ++j)
            v[j] = f2bf(w1_W2[(ks * 32 + quad * 8 + j) * 32 + n]);
    } else if (blk < 38) {          // vq column tiles
        const int ks = blk - 36;
        #pragma unroll
        for (int j = 0; j < 8; ++j)
            v[j] = (l16 == 0) ? f2bf(vq[ks * 32 + quad * 8 + j]) : (short)0;
    } else if (blk < 54) {          // bigW1 [64 x 128] = [wf_W1 | hb_W | v_W1]
        const int t = blk - 38, ks = t >> 3, n = (t & 7) * 16 + l16;
        #pragma unroll
        for (int j = 0; j < 8; ++j) {
            const int k = ks * 32 + quad * 8 + j;
            float w;
            if (n < 64)       w = wf_W1[k * 64 + n];
            else if (n < 96)  w = hb_W[k * 32 + (n - 64)];
            else              w = v_W1[k * 32 + (n - 96)];
            v[j] = f2bf(w);
        }
    } else {                        // 54-57: wf_W2 [64 x 32]
        const int t = blk - 54, ks = t >> 1, n = (t & 1) * 16 + l16;
        #pragma unroll
        for (int j = 0; j < 8; ++j)
            v[j] = f2bf(wf_W2[(ks * 32 + quad * 8 + j) * 32 + n]);
    }
    *(bs8*)&fb[(size_t)blk * 512 + lane * 8] = v;
}

// ---------------- main: WPB sites per block, one per wave ----------------
struct __align__(16) WaveLds {
    short entb[16][72];   // bf16 embeds (144B rows: 16B-aligned, 2-way banks)
    short scr[16][72];    // t (bf16), then hall (bf16)
    short aoutb[64];      // bf16 attn_out
    short hb16[64];       // bf16 wf hidden
    float qs[8];
};

__global__ __launch_bounds__(64 * WPB, 4)
void qmix_main(const float* __restrict__ agent_qs,
               const float* __restrict__ ally, const float* __restrict__ enemy,
               const float* __restrict__ b_al, const float* __restrict__ b_en,
               const float* __restrict__ w1_b1, const float* __restrict__ w1_b2,
               const float* __restrict__ wf_b1, const float* __restrict__ wf_b2,
               const float* __restrict__ hb_b,  const float* __restrict__ v_b1,
               const float* __restrict__ v_W2,  const float* __restrict__ v_b2,
               const short* __restrict__ fb,
               float* __restrict__ out)
{
    const int w    = threadIdx.x >> 6;
    const int lane = threadIdx.x & 63;
    const int site = blockIdx.x * WPB + w;
    const int quad = lane >> 4, l16 = lane & 15;

    __shared__ WaveLds lds[WPB];
    WaveLds& L = lds[w];

    if (lane < 8) L.qs[lane] = agent_qs[(size_t)site * 8 + lane];

    // ---- encoder A-frags: ally rows 0-7, enemy rows 8-15 (others exact zero) ----
    bs8 a_al = {0,0,0,0,0,0,0,0}, a_en = {0,0,0,0,0,0,0,0};
    if (l16 < 8) {
        const float* pa = ally + ((size_t)l16 * BS_ + site) * 32 + quad * 8;
        const float4 f0 = *(const float4*)pa, f1 = *(const float4*)(pa + 4);
        a_al[0]=f2bf(f0.x); a_al[1]=f2bf(f0.y); a_al[2]=f2bf(f0.z); a_al[3]=f2bf(f0.w);
        a_al[4]=f2bf(f1.x); a_al[5]=f2bf(f1.y); a_al[6]=f2bf(f1.z); a_al[7]=f2bf(f1.w);
    } else if (quad < 2) {   // enemy K=16: quads 0,1 only
        const float* pe = enemy + ((size_t)(l16 - 8) * BS_ + site) * 16 + quad * 8;
        const float4 f0 = *(const float4*)pe, f1 = *(const float4*)(pe + 4);
        a_en[0]=f2bf(f0.x); a_en[1]=f2bf(f0.y); a_en[2]=f2bf(f0.z); a_en[3]=f2bf(f0.w);
        a_en[4]=f2bf(f1.x); a_en[5]=f2bf(f1.y); a_en[6]=f2bf(f1.z); a_en[7]=f2bf(f1.w);
    }

    // ---- encoders: D rows 0-7 = ally@W_al, rows 8-15 = enemy@W_en ----
    f4 encf[4];   // fp32 embeds kept in regs for attn_out epilogue
    #pragma unroll
    for (int n0t = 0; n0t < 4; ++n0t) {
        f4 acc = {0.f, 0.f, 0.f, 0.f};
        acc = MFMA(a_al, LOADB(8 + n0t), acc);
        acc = MFMA(a_en, LOADB(12 + n0t), acc);
        const int d = n0t * 16 + l16;
        const float bal = b_al[d], ben = b_en[d];
        #pragma unroll
        for (int r = 0; r < 4; ++r) {
            const int row = quad * 4 + r;
            const float v = acc[r] + (row < 8 ? bal : ben);
            encf[n0t][r] = v;
            L.entb[row][d] = f2bf(v);
        }
    }
    __syncthreads();   // B1

    // ---- t = ent @ M ; pq = ent @ vq (MFMA, col-0 tiles) ----
    const bs8 ae0 = *(const bs8*)&L.entb[l16][quad * 8];
    const bs8 ae1 = *(const bs8*)&L.entb[l16][32 + quad * 8];
    f4 pqacc = {0.f, 0.f, 0.f, 0.f};
    pqacc = MFMA(ae0, LOADB(36), pqacc);
    pqacc = MFMA(ae1, LOADB(37), pqacc);
    #pragma unroll
    for (int n0t = 0; n0t < 4; ++n0t) {
        f4 acc = {0.f, 0.f, 0.f, 0.f};
        acc = MFMA(ae0, LOADB(0 + n0t), acc);
        acc = MFMA(ae1, LOADB(4 + n0t), acc);
        const int d = n0t * 16 + l16;
        #pragma unroll
        for (int r = 0; r < 4; ++r) L.scr[quad * 4 + r][d] = f2bf(acc[r]);
    }
    __syncthreads();   // B2

    // ---- energy = t @ ent^T + pq  (rows quad*4+r, col l16; pq bcast via shfl) ----
    f4 eacc = {0.f, 0.f, 0.f, 0.f};
    {
        const bs8 at0 = *(const bs8*)&L.scr[l16][quad * 8];
        const bs8 at1 = *(const bs8*)&L.scr[l16][32 + quad * 8];
        eacc = MFMA(at0, ae0, eacc);
        eacc = MFMA(at1, ae1, eacc);
        const int src = lane & 48;   // l16==0 lane of this quad holds pq[row]
        #pragma unroll
        for (int r = 0; r < 4; ++r) eacc[r] += __shfl(pqacc[r], src, 64);
    }

    // ---- softmax over rows i (per col j=l16), in registers ----
    float amean_r[4];
    {
        float cmax = fmaxf(fmaxf(eacc[0], eacc[1]), fmaxf(eacc[2], eacc[3]));
        cmax = fmaxf(cmax, __shfl_xor(cmax, 16, 64));
        cmax = fmaxf(cmax, __shfl_xor(cmax, 32, 64));
        float er[4], csum = 0.f;
        #pragma unroll
        for (int r = 0; r < 4; ++r) { er[r] = __expf(eacc[r] - cmax); csum += er[r]; }
        csum += __shfl_xor(csum, 16, 64);
        csum += __shfl_xor(csum, 32, 64);
        const float inv = 1.f / csum;
        #pragma unroll
        for (int r = 0; r < 4; ++r) {
            float p = er[r] * inv;              // attn[row][col]
            p += __shfl_xor(p, 1, 64);          // row-mean over cols (l16 butterfly)
            p += __shfl_xor(p, 2, 64);
            p += __shfl_xor(p, 4, 64);
            p += __shfl_xor(p, 8, 64);
            amean_r[r] = p * (1.f / 16.f);
        }
    }

    // ---- attn_out: aout[n0t*16+l16] = sum_rows amean*encf, quad-reduced ----
    #pragma unroll
    for (int n0t = 0; n0t < 4; ++n0t) {
        float ap = amean_r[0] * encf[n0t][0] + amean_r[1] * encf[n0t][1]
                 + amean_r[2] * encf[n0t][2] + amean_r[3] * encf[n0t][3];
        ap += __shfl_xor(ap, 16, 64);
        ap += __shfl_xor(ap, 32, 64);
        if (quad == 0) L.aoutb[n0t * 16 + l16] = f2bf(ap);
    }
    __syncthreads();   // B3

    // ---- all-rows-equal A-frags of aout (wave-uniform LDS addr per k-group) ----
    const bs8 a0 = *(const bs8*)&L.aoutb[quad * 8];        // k 0..31
    const bs8 a1 = *(const bs8*)&L.aoutb[32 + quad * 8];   // k 32..63

    // ---- pass1: x[n] = aout @ [wf_W1 | hb_W | v_W1], n = n0t*16+l16 ----
    float x[8];
    #pragma unroll
    for (int n0t = 0; n0t < 8; ++n0t) {
        f4 acc = {0.f, 0.f, 0.f, 0.f};
        acc = MFMA(a0, LOADB(38 + n0t), acc);
        acc = MFMA(a1, LOADB(46 + n0t), acc);
        x[n0t] = acc[0];   // all D rows equal
    }
    // wf hidden: h[lane] = relu(x[quad] + wf_b1[lane])  (col = quad*16+l16 = lane)
    {
        const float xh = (quad == 0) ? x[0] : (quad == 1) ? x[1]
                       : (quad == 2) ? x[2] : x[3];
        L.hb16[lane] = f2bf(fmaxf(xh + wf_b1[lane], 0.f));
    }
    // hyper bias b1 (valid lanes<32): col = lane
    const float b1m = ((lane < 16) ? x[4] : x[5]) + ((lane < 32) ? hb_b[lane] : 0.f);
    // v net: cols l16 (x[6]) and 16+l16 (x[7]); reduce over l16 group
    float vsum;
    {
        float hv = fmaxf(x[6] + v_b1[l16], 0.f)      * v_W2[l16]
                 + fmaxf(x[7] + v_b1[16 + l16], 0.f) * v_W2[16 + l16];
        hv += __shfl_xor(hv, 1, 64);
        hv += __shfl_xor(hv, 2, 64);
        hv += __shfl_xor(hv, 4, 64);
        hv += __shfl_xor(hv, 8, 64);
        vsum = hv;   // equal across quads
    }
    __syncthreads();   // B4

    // ---- wf layer2 via MFMA (all-rows-equal h A-frag) ----
    float wfm;
    {
        const bs8 h0 = *(const bs8*)&L.hb16[quad * 8];
        const bs8 h1 = *(const bs8*)&L.hb16[32 + quad * 8];
        f4 acc0 = {0.f, 0.f, 0.f, 0.f};
        acc0 = MFMA(h0, LOADB(54), acc0);
        acc0 = MFMA(h1, LOADB(56), acc0);
        f4 acc1 = {0.f, 0.f, 0.f, 0.f};
        acc1 = MFMA(h0, LOADB(55), acc1);
        acc1 = MFMA(h1, LOADB(57), acc1);
        const float w0 = fabsf(acc0[0] + wf_b2[l16]);        // cols 0-15
        const float w1 = fabsf(acc1[0] + wf_b2[16 + l16]);   // cols 16-31
        wfm = (lane < 16) ? w0 : w1;                          // valid lanes<32
    }

    // ---- agent hypernet L1: emi[16x128] @ w1_W1[128x64] (rows 0-7 = agents) ----
    #pragma unroll
    for (int n0t = 0; n0t < 4; ++n0t) {
        f4 acc = {0.f, 0.f, 0.f, 0.f};
        acc = MFMA(a0,  LOADB(16 + 0 + n0t), acc);
        acc = MFMA(a1,  LOADB(16 + 4 + n0t), acc);
        acc = MFMA(ae0, LOADB(16 + 8 + n0t), acc);
        acc = MFMA(ae1, LOADB(16 + 12 + n0t), acc);
        const int d = n0t * 16 + l16;
        const float b1v = w1_b1[d];
        #pragma unroll
        for (int r = 0; r < 4; ++r) {
            const int row = quad * 4 + r;
            if (row < 8)
                L.scr[row][d] = f2bf(fmaxf(acc[r] + b1v, 0.f));
        }
    }
    __syncthreads();   // B5

    // ---- agent hypernet L2 + mixing partials (shuffle-reduced) ----
    float p0 = 0.f, p1 = 0.f;
    {
        const bs8 ah0 = *(const bs8*)&L.scr[l16][quad * 8];
        const bs8 ah1 = *(const bs8*)&L.scr[l16][32 + quad * 8];
        #pragma unroll
        for (int n0t = 0; n0t < 2; ++n0t) {
            f4 acc = {0.f, 0.f, 0.f, 0.f};
            acc = MFMA(ah0, LOADB(32 + 0 + n0t), acc);
            acc = MFMA(ah1, LOADB(32 + 2 + n0t), acc);
            const int col = n0t * 16 + l16;
            const float b2v = w1_b2[col];
            float p = 0.f;
            if (quad < 2) {       // rows 0-7 = agents; rows 8-15 stale (discard)
                #pragma unroll
                for (int r = 0; r < 4; ++r)
                    p += L.qs[quad * 4 + r] * fabsf(acc[r] + b2v);
            }
            if (n0t == 0) p0 = p; else p1 = p;
        }
        p0 += __shfl_xor(p0, 16, 64);   // quad0+quad1 = all 8 agents (cols 0-15)
        p1 += __shfl_xor(p1, 16, 64);   // cols 16-31 (valid at quads 0,1)
    }

    // ---- elu, mix, reduce over m (lanes 0..31 hold cols 0..31) ----
    float contrib = 0.f;
    if (lane < 32) {
        float hp = (lane < 16 ? p0 : p1) + b1m;
        hp = (hp > 0.f) ? hp : (__expf(hp) - 1.f);
        contrib = hp * wfm;
    }
    #pragma unroll
    for (int off = 16; off >= 1; off >>= 1)
        contrib += __shfl_down(contrib, off, 64);
    if (lane == 0) out[site] = contrib + vsum + v_b2[0];
}

extern "C" void kernel_launch(void* const* d_in, const int* in_sizes, int n_in,
                              void* d_out, int out_size, void* d_ws, size_t ws_size,
                              hipStream_t stream) {
    const float* p[25];
    for (int i = 0; i < 25; ++i) p[i] = (const float*)d_in[i];
    // 0 agent_qs 1 ally 2 enemy 3 W_al 4 b_al 5 W_en 6 b_en 7 Wq 8 bq 9 Wk 10 bk
    // 11 w1_W1 12 w1_b1 13 w1_W2 14 w1_b2 15 wf_W1 16 wf_b1 17 wf_W2 18 wf_b2
    // 19 hb_W 20 hb_b 21 v_W1 22 v_b1 23 v_W2 24 v_b2
    short* fb = (short*)d_ws;                           // 58 tiles * 512 bf16
    float* vq = (float*)((char*)d_ws + 58 * 512 * 2);   // 64 floats
    float* Ms = vq + 64;                                // 64*64 floats

    qmix_pre1<<<4096 + 64, 64, 0, stream>>>(p[7], p[9], p[10], Ms, vq);
    qmix_pack<<<58, 64, 0, stream>>>(Ms, p[3], p[5], p[11], p[13], vq,
                                     p[15], p[19], p[21], p[17], fb);
    qmix_main<<<BS_ / WPB, 64 * WPB, 0, stream>>>(
        p[0], p[1], p[2], p[4], p[6], p[12], p[14],
        p[16], p[18], p[20], p[22], p[23], p[24],
        fb, (float*)d_out);
}

// Round 10
// 155.027 us; speedup vs baseline: 6.5502x; 1.0529x over previous
//
#include <hip/hip_runtime.h>
#include <hip/hip_bf16.h>

// QMixer forward, MI355X gfx950. fp32 in/out, bf16 MFMA for all matmul blocks.
// B=128 S=128 A=8 En=8 E=16 NFal=32 NFen=16 D=64 Da=128 M=32 H=64.
// Algebra (verified R4): softmax over query axis i cancels per-column-j terms:
//   energy[i][j] = e_i (Wq Wk^T/sqrt(Da)) e_j^T + e_i.(Wq bk)/sqrt(Da)
// R10: 2 sites per wave, stacked in the 16-row MFMA dimension for the epilogue
// nets (rows 0-7 = site0, 8-15 = site1): pass1/wfL2/hypernet L1+L2 run once
// for both sites. 80 MFMAs / 2 sites vs 2x60; 6 barriers / 2 sites.
// ent->t->hall alias one LDS buffer per site (B1b protects overwrite).
// MFMA 16x16x32 layouts (HW-verified): A[m=lane&15][k=quad*8+j],
// B[k=quad*8+j][n=lane&15], C/D[row=quad*4+r][col=lane&15].

#define B_   128
#define S_   128
#define BS_  (B_ * S_)
#define INV_S 0.08838834764831845f  // 1/sqrt(128)

typedef short bs8 __attribute__((ext_vector_type(8)));
typedef float f4  __attribute__((ext_vector_type(4)));

#define MFMA(a, b, c) __builtin_amdgcn_mfma_f32_16x16x32_bf16((a), (b), (c), 0, 0, 0)
#define LOADB(t) (*(const bs8*)&fb[(size_t)(t) * 512 + lane * 8])

__device__ __forceinline__ short f2bf(float f) {
    union { float f; unsigned u; } v; v.f = f;
    unsigned r = v.u + 0x7fffu + ((v.u >> 16) & 1u);   // RNE
    return (short)(r >> 16);
}

// ---------------- pre1: M (one wave per element) and vq ----------------
__global__ __launch_bounds__(64)
void qmix_pre1(const float* __restrict__ Wq, const float* __restrict__ Wk,
               const float* __restrict__ bk,
               float* __restrict__ Ms, float* __restrict__ vq)
{
    const int blk = blockIdx.x, t = threadIdx.x;
    float p;
    if (blk < 4096) {
        const int k = blk >> 6, n = blk & 63;
        p = Wq[k * 128 + t] * Wk[n * 128 + t]
          + Wq[k * 128 + 64 + t] * Wk[n * 128 + 64 + t];
        #pragma unroll
        for (int off = 32; off >= 1; off >>= 1) p += __shfl_down(p, off, 64);
        if (t == 0) Ms[k * 64 + n] = p * INV_S;
    } else {
        const int d = blk - 4096;
        p = Wq[d * 128 + t] * bk[t] + Wq[d * 128 + 64 + t] * bk[64 + t];
        #pragma unroll
        for (int off = 32; off >= 1; off >>= 1) p += __shfl_down(p, off, 64);
        if (t == 0) vq[d] = p * INV_S;
    }
}

// ---------------- pack: bf16 B-fragment tiles ----------------
// frag tile = 512 bf16: [lane][j], elem j = W[k = ks*32+quad*8+j][n = n0+l16]
// tiles: 0-7 M(ks*4+n0t) | 8-11 W_al | 12-15 W_en(K=16 zero-pad) |
//        16-31 w1_W1(16+ks*4+n0t) | 32-35 w1_W2(32+ks*2+n0t) | 36-37 vq col |
//        38-53 bigW1=[wf_W1|hb_W|v_W1] (38+ks*8+n0t) | 54-57 wf_W2(54+ks*2+n0t)
__global__ __launch_bounds__(64)
void qmix_pack(const float* __restrict__ Ms,
               const float* __restrict__ W_al, const float* __restrict__ W_en,
               const float* __restrict__ w1_W1, const float* __restrict__ w1_W2,
               const float* __restrict__ vq,
               const float* __restrict__ wf_W1, const float* __restrict__ hb_W,
               const float* __restrict__ v_W1,  const float* __restrict__ wf_W2,
               short* __restrict__ fb)
{
    const int blk = blockIdx.x, lane = threadIdx.x;
    const int quad = lane >> 4, l16 = lane & 15;
    bs8 v;
    if (blk < 8) {
        const int ks = blk >> 2, n = (blk & 3) * 16 + l16;
        #pragma unroll
        for (int j = 0; j < 8; ++j)
            v[j] = f2bf(Ms[(ks * 32 + quad * 8 + j) * 64 + n]);
    } else if (blk < 16) {
        const bool en = (blk >= 12);
        const float* W = en ? W_en : W_al;
        const int Krows = en ? 16 : 32;
        const int n = ((blk - (en ? 12 : 8)) & 3) * 16 + l16;
        #pragma unroll
        for (int j = 0; j < 8; ++j) {
            const int k = quad * 8 + j;
            v[j] = (k < Krows) ? f2bf(W[k * 64 + n]) : (short)0;
        }
    } else if (blk < 32) {
        const int t = blk - 16, ks = t >> 2, n = (t & 3) * 16 + l16;
        #pragma unroll
        for (int j = 0; j < 8; ++j)
            v[j] = f2bf(w1_W1[(ks * 32 + quad * 8 + j) * 64 + n]);
    } else if (blk < 36) {
        const int t = blk - 32, ks = t >> 1, n = (t & 1) * 16 + l16;
        #pragma unroll
        for (int j = 0; j < 8; ++j)
            v[j] = f2bf(w1_W2[(ks * 32 + quad * 8 + j) * 32 + n]);
    } else if (blk < 38) {          // vq column tiles
        const int ks = blk - 36;
        #pragma unroll
        for (int j = 0; j < 8; ++j)
            v[j] = (l16 == 0) ? f2bf(vq[ks * 32 + quad * 8 + j]) : (short)0;
    } else if (blk < 54) {          // bigW1 [64 x 128] = [wf_W1 | hb_W | v_W1]
        const int t = blk - 38, ks = t >> 3, n = (t & 7) * 16 + l16;
        #pragma unroll
        for (int j = 0; j < 8; ++j) {
            const int k = ks * 32 + quad * 8 + j;
            float w;
            if (n < 64)       w = wf_W1[k * 64 + n];
            else if (n < 96)  w = hb_W[k * 32 + (n - 64)];
            else              w = v_W1[k * 32 + (n - 96)];
            v[j] = f2bf(w);
        }
    } else {                        // 54-57: wf_W2 [64 x 32]
        const int t = blk - 54, ks = t >> 1, n = (t & 1) * 16 + l16;
        #pragma unroll
        for (int j = 0; j < 8; ++j)
            v[j] = f2bf(wf_W2[(ks * 32 + quad * 8 + j) * 32 + n]);
    }
    *(bs8*)&fb[(size_t)blk * 512 + lane * 8] = v;
}

// ---------------- main: 2 waves/block, 2 sites/wave ----------------
struct __align__(16) WaveLds {
    short ent[2][16][72];  // per site: ent -> t; ent[0] also reused as hall
    short aoutb[2][64];    // bf16 attn_out per site
    short hb16[2][64];     // bf16 wf hidden per site
    float qs[2][8];
};

__global__ __launch_bounds__(128, 4)
void qmix_main(const float* __restrict__ agent_qs,
               const float* __restrict__ ally, const float* __restrict__ enemy,
               const float* __restrict__ b_al, const float* __restrict__ b_en,
               const float* __restrict__ w1_b1, const float* __restrict__ w1_b2,
               const float* __restrict__ wf_b1, const float* __restrict__ wf_b2,
               const float* __restrict__ hb_b,  const float* __restrict__ v_b1,
               const float* __restrict__ v_W2,  const float* __restrict__ v_b2,
               const short* __restrict__ fb,
               float* __restrict__ out)
{
    const int w    = threadIdx.x >> 6;
    const int lane = threadIdx.x & 63;
    const int quad = lane >> 4, l16 = lane & 15;
    const int half = lane >> 5;      // final-stage site of this lane
    const int qh   = quad & 1;
    const int siteA = blockIdx.x * 4 + w * 2;   // sites siteA, siteA+1

    __shared__ WaveLds lds[2];
    WaveLds& L = lds[w];

    if (lane < 16)
        L.qs[lane >> 3][lane & 7] =
            agent_qs[(size_t)(siteA + (lane >> 3)) * 8 + (lane & 7)];

    // ---- encoders per site: D rows 0-7 ally, 8-15 enemy ----
    f4 encf[2][4];
    #pragma unroll
    for (int s = 0; s < 2; ++s) {
        const int site = siteA + s;
        bs8 a_al = {0,0,0,0,0,0,0,0}, a_en = {0,0,0,0,0,0,0,0};
        if (l16 < 8) {
            const float* pa = ally + ((size_t)l16 * BS_ + site) * 32 + quad * 8;
            const float4 f0 = *(const float4*)pa, f1 = *(const float4*)(pa + 4);
            a_al[0]=f2bf(f0.x); a_al[1]=f2bf(f0.y); a_al[2]=f2bf(f0.z); a_al[3]=f2bf(f0.w);
            a_al[4]=f2bf(f1.x); a_al[5]=f2bf(f1.y); a_al[6]=f2bf(f1.z); a_al[7]=f2bf(f1.w);
        } else if (quad < 2) {   // enemy K=16: quads 0,1 only
            const float* pe = enemy + ((size_t)(l16 - 8) * BS_ + site) * 16 + quad * 8;
            const float4 f0 = *(const float4*)pe, f1 = *(const float4*)(pe + 4);
            a_en[0]=f2bf(f0.x); a_en[1]=f2bf(f0.y); a_en[2]=f2bf(f0.z); a_en[3]=f2bf(f0.w);
            a_en[4]=f2bf(f1.x); a_en[5]=f2bf(f1.y); a_en[6]=f2bf(f1.z); a_en[7]=f2bf(f1.w);
        }
        #pragma unroll
        for (int n0t = 0; n0t < 4; ++n0t) {
            f4 acc = {0.f, 0.f, 0.f, 0.f};
            acc = MFMA(a_al, LOADB(8 + n0t), acc);
            acc = MFMA(a_en, LOADB(12 + n0t), acc);
            const int d = n0t * 16 + l16;
            const float bal = b_al[d], ben = b_en[d];
            #pragma unroll
            for (int r = 0; r < 4; ++r) {
                const int row = quad * 4 + r;
                const float v = acc[r] + (row < 8 ? bal : ben);
                encf[s][n0t][r] = v;
                L.ent[s][row][d] = f2bf(v);
            }
        }
    }
    __syncthreads();   // B1: ent ready

    // ---- A-frags from ent: per-site rows (ae) + cross-site agent rows (ag) ----
    bs8 ae0s[2], ae1s[2];
    #pragma unroll
    for (int s = 0; s < 2; ++s) {
        ae0s[s] = *(const bs8*)&L.ent[s][l16][quad * 8];
        ae1s[s] = *(const bs8*)&L.ent[s][l16][32 + quad * 8];
    }
    const short (*entP)[72] = (l16 < 8) ? L.ent[0] : L.ent[1];
    const bs8 ag0 = *(const bs8*)&entP[l16 & 7][quad * 8];
    const bs8 ag1 = *(const bs8*)&entP[l16 & 7][32 + quad * 8];
    __syncthreads();   // B1b: ent reads done, t overwrite safe

    // ---- t = ent @ M ; pq = ent @ vq (per site; t into ent buffer) ----
    f4 pqs[2];
    #pragma unroll
    for (int s = 0; s < 2; ++s) {
        f4 pq = {0.f, 0.f, 0.f, 0.f};
        pq = MFMA(ae0s[s], LOADB(36), pq);
        pq = MFMA(ae1s[s], LOADB(37), pq);
        pqs[s] = pq;
        #pragma unroll
        for (int n0t = 0; n0t < 4; ++n0t) {
            f4 acc = {0.f, 0.f, 0.f, 0.f};
            acc = MFMA(ae0s[s], LOADB(0 + n0t), acc);
            acc = MFMA(ae1s[s], LOADB(4 + n0t), acc);
            const int d = n0t * 16 + l16;
            #pragma unroll
            for (int r = 0; r < 4; ++r) L.ent[s][quad * 4 + r][d] = f2bf(acc[r]);
        }
    }
    __syncthreads();   // B2: t ready

    // ---- energy + softmax + attn_out per site (interleaved chains) ----
    #pragma unroll
    for (int s = 0; s < 2; ++s) {
        f4 eacc = {0.f, 0.f, 0.f, 0.f};
        {
            const bs8 at0 = *(const bs8*)&L.ent[s][l16][quad * 8];
            const bs8 at1 = *(const bs8*)&L.ent[s][l16][32 + quad * 8];
            eacc = MFMA(at0, ae0s[s], eacc);
            eacc = MFMA(at1, ae1s[s], eacc);
            const int src = lane & 48;
            #pragma unroll
            for (int r = 0; r < 4; ++r) eacc[r] += __shfl(pqs[s][r], src, 64);
        }
        float cmax = fmaxf(fmaxf(eacc[0], eacc[1]), fmaxf(eacc[2], eacc[3]));
        cmax = fmaxf(cmax, __shfl_xor(cmax, 16, 64));
        cmax = fmaxf(cmax, __shfl_xor(cmax, 32, 64));
        float er[4], csum = 0.f;
        #pragma unroll
        for (int r = 0; r < 4; ++r) { er[r] = __expf(eacc[r] - cmax); csum += er[r]; }
        csum += __shfl_xor(csum, 16, 64);
        csum += __shfl_xor(csum, 32, 64);
        const float inv = 1.f / csum;
        float amean[4];
        #pragma unroll
        for (int r = 0; r < 4; ++r) {
            float p = er[r] * inv;
            p += __shfl_xor(p, 1, 64);
            p += __shfl_xor(p, 2, 64);
            p += __shfl_xor(p, 4, 64);
            p += __shfl_xor(p, 8, 64);
            amean[r] = p * (1.f / 16.f);
        }
        #pragma unroll
        for (int n0t = 0; n0t < 4; ++n0t) {
            float ap = amean[0] * encf[s][n0t][0] + amean[1] * encf[s][n0t][1]
                     + amean[2] * encf[s][n0t][2] + amean[3] * encf[s][n0t][3];
            ap += __shfl_xor(ap, 16, 64);
            ap += __shfl_xor(ap, 32, 64);
            if (quad == 0) L.aoutb[s][n0t * 16 + l16] = f2bf(ap);
        }
    }
    __syncthreads();   // B3: aoutb ready

    // ---- stacked aout A-frag: rows 0-7 site0, 8-15 site1 ----
    const short* aoP = L.aoutb[l16 >> 3];
    const bs8 aab0 = *(const bs8*)&aoP[quad * 8];
    const bs8 aab1 = *(const bs8*)&aoP[32 + quad * 8];

    // ---- pass1: x = aout @ [wf_W1 | hb_W | v_W1] for both sites at once ----
    float xm[8];   // lane's half-site values, cols n0t*16+l16
    #pragma unroll
    for (int n0t = 0; n0t < 8; ++n0t) {
        f4 acc = {0.f, 0.f, 0.f, 0.f};
        acc = MFMA(aab0, LOADB(38 + n0t), acc);
        acc = MFMA(aab1, LOADB(46 + n0t), acc);
        xm[n0t] = acc[0];   // rows within a site identical
    }
    // wf hidden for own site (quads of a half write duplicate values, benign)
    #pragma unroll
    for (int n0t = 0; n0t < 4; ++n0t) {
        const int t = n0t * 16 + l16;
        L.hb16[half][t] = f2bf(fmaxf(xm[n0t] + wf_b1[t], 0.f));
    }
    const int m32 = lane & 31;
    const float b1m = xm[4 + qh] + hb_b[m32];
    float vsum;
    {
        float hv = fmaxf(xm[6 + qh] + v_b1[m32], 0.f) * v_W2[m32];
        hv += __shfl_xor(hv, 1, 64);
        hv += __shfl_xor(hv, 2, 64);
        hv += __shfl_xor(hv, 4, 64);
        hv += __shfl_xor(hv, 8, 64);
        hv += __shfl_xor(hv, 16, 64);
        vsum = hv;   // per-half v_s
    }
    __syncthreads();   // B4: hb16 ready

    // ---- wf layer2, both sites stacked (rows by l16>>3) ----
    float wfm;
    {
        const short* hfP = L.hb16[l16 >> 3];
        const bs8 hf0 = *(const bs8*)&hfP[quad * 8];
        const bs8 hf1 = *(const bs8*)&hfP[32 + quad * 8];
        f4 acc0 = {0.f, 0.f, 0.f, 0.f};
        acc0 = MFMA(hf0, LOADB(54), acc0);
        acc0 = MFMA(hf1, LOADB(56), acc0);
        f4 acc1 = {0.f, 0.f, 0.f, 0.f};
        acc1 = MFMA(hf0, LOADB(55), acc1);
        acc1 = MFMA(hf1, LOADB(57), acc1);
        wfm = fabsf((qh ? acc1[0] : acc0[0]) + wf_b2[m32]);
    }

    // ---- agent hypernet L1, both sites stacked (agents: rows l16>>3 / l16&7) ----
    #pragma unroll
    for (int n0t = 0; n0t < 4; ++n0t) {
        f4 acc = {0.f, 0.f, 0.f, 0.f};
        acc = MFMA(aab0, LOADB(16 + 0 + n0t), acc);
        acc = MFMA(aab1, LOADB(16 + 4 + n0t), acc);
        acc = MFMA(ag0,  LOADB(16 + 8 + n0t), acc);
        acc = MFMA(ag1,  LOADB(16 + 12 + n0t), acc);
        const int d = n0t * 16 + l16;
        const float b1v = w1_b1[d];
        #pragma unroll
        for (int r = 0; r < 4; ++r)
            L.ent[0][quad * 4 + r][d] = f2bf(fmaxf(acc[r] + b1v, 0.f));  // hall
    }
    __syncthreads();   // B5: hall ready

    // ---- hypernet L2 + mixing partials (rows = stacked agents) ----
    float pm;
    {
        const bs8 ha0 = *(const bs8*)&L.ent[0][l16][quad * 8];
        const bs8 ha1 = *(const bs8*)&L.ent[0][l16][32 + quad * 8];
        const float* qsv = L.qs[half];
        float p0 = 0.f, p1 = 0.f;
        #pragma unroll
        for (int n0t = 0; n0t < 2; ++n0t) {
            f4 acc = {0.f, 0.f, 0.f, 0.f};
            acc = MFMA(ha0, LOADB(32 + 0 + n0t), acc);
            acc = MFMA(ha1, LOADB(32 + 2 + n0t), acc);
            const float b2v = w1_b2[n0t * 16 + l16];
            float p = 0.f;
            #pragma unroll
            for (int r = 0; r < 4; ++r)
                p += qsv[qh * 4 + r] * fabsf(acc[r] + b2v);
            if (n0t == 0) p0 = p; else p1 = p;
        }
        p0 += __shfl_xor(p0, 16, 64);   // agents 0-3 + 4-7 within each site
        p1 += __shfl_xor(p1, 16, 64);
        pm = qh ? p1 : p0;               // lane's col m32 value
    }

    // ---- elu, mix, half-reduce (lanes 0-31 site0, 32-63 site1) ----
    float hp = pm + b1m;
    hp = (hp > 0.f) ? hp : (__expf(hp) - 1.f);
    float contrib = hp * wfm;
    contrib += __shfl_xor(contrib, 1, 64);
    contrib += __shfl_xor(contrib, 2, 64);
    contrib += __shfl_xor(contrib, 4, 64);
    contrib += __shfl_xor(contrib, 8, 64);
    contrib += __shfl_xor(contrib, 16, 64);
    if ((lane & 31) == 0)
        out[siteA + half] = contrib + vsum + v_b2[0];
}

extern "C" void kernel_launch(void* const* d_in, const int* in_sizes, int n_in,
                              void* d_out, int out_size, void* d_ws, size_t ws_size,
                              hipStream_t stream) {
    const float* p[25];
    for (int i = 0; i < 25; ++i) p[i] = (const float*)d_in[i];
    // 0 agent_qs 1 ally 2 enemy 3 W_al 4 b_al 5 W_en 6 b_en 7 Wq 8 bq 9 Wk 10 bk
    // 11 w1_W1 12 w1_b1 13 w1_W2 14 w1_b2 15 wf_W1 16 wf_b1 17 wf_W2 18 wf_b2
    // 19 hb_W 20 hb_b 21 v_W1 22 v_b1 23 v_W2 24 v_b2
    short* fb = (short*)d_ws;                           // 58 tiles * 512 bf16
    float* vq = (float*)((char*)d_ws + 58 * 512 * 2);   // 64 floats
    float* Ms = vq + 64;                                // 64*64 floats

    qmix_pre1<<<4096 + 64, 64, 0, stream>>>(p[7], p[9], p[10], Ms, vq);
    qmix_pack<<<58, 64, 0, stream>>>(Ms, p[3], p[5], p[11], p[13], vq,
                                     p[15], p[19], p[21], p[17], fb);
    qmix_main<<<BS_ / 4, 128, 0, stream>>>(
        p[0], p[1], p[2], p[4], p[6], p[12], p[14],
        p[16], p[18], p[20], p[22], p[23], p[24],
        fb, (float*)d_out);
}

// Round 11
// 153.242 us; speedup vs baseline: 6.6265x; 1.0116x over previous
//
#include <hip/hip_runtime.h>
#include <hip/hip_bf16.h>

// QMixer forward, MI355X gfx950. fp32 in/out, bf16 MFMA for all matmul blocks.
// B=128 S=128 A=8 En=8 E=16 NFal=32 NFen=16 D=64 Da=128 M=32 H=64.
// Algebra (verified R4): softmax over query axis i cancels per-column-j terms:
//   energy[i][j] = e_i (Wq Wk^T/sqrt(Da)) e_j^T + e_i.(Wq bk)/sqrt(Da)
// R11: (1) ent persistent in LDS; t -> separate scr buffer; attn_out re-reads
// bf16 ent (kills encf's 32 long-lived AGPRs; occupancy 3->4 waves/SIMD);
// (2) pre1 merged into pack (M-tiles computed in-tile); 2 kernels total.
// MFMA 16x16x32 layouts (HW-verified): A[m=lane&15][k=quad*8+j],
// B[k=quad*8+j][n=lane&15], C/D[row=quad*4+r][col=lane&15].

#define B_   128
#define S_   128
#define BS_  (B_ * S_)
#define INV_S 0.08838834764831845f  // 1/sqrt(128)

typedef short bs8 __attribute__((ext_vector_type(8)));
typedef float f4  __attribute__((ext_vector_type(4)));

#define MFMA(a, b, c) __builtin_amdgcn_mfma_f32_16x16x32_bf16((a), (b), (c), 0, 0, 0)
#define LOADB(t) (*(const bs8*)&fb[(size_t)(t) * 512 + lane * 8])

__device__ __forceinline__ short f2bf(float f) {
    union { float f; unsigned u; } v; v.f = f;
    unsigned r = v.u + 0x7fffu + ((v.u >> 16) & 1u);   // RNE
    return (short)(r >> 16);
}
__device__ __forceinline__ float bf2f(short s) {
    union { unsigned u; float f; } v;
    v.u = ((unsigned)(unsigned short)s) << 16;
    return v.f;
}

// ---------------- pack: bf16 B-fragment tiles (self-contained) ----------------
// frag tile = 512 bf16: [lane][j], elem j = W[k = ks*32+quad*8+j][n = n0+l16]
// tiles: 0-7 M(ks*4+n0t, computed in-tile) | 8-11 W_al | 12-15 W_en(K=16 pad) |
//        16-31 w1_W1 | 32-35 w1_W2 | 36-37 vq col (computed in-tile) |
//        38-53 bigW1=[wf_W1|hb_W|v_W1] | 54-57 wf_W2
__global__ __launch_bounds__(64)
void qmix_pack(const float* __restrict__ Wq,   const float* __restrict__ Wk,
               const float* __restrict__ bk,
               const float* __restrict__ W_al, const float* __restrict__ W_en,
               const float* __restrict__ w1_W1, const float* __restrict__ w1_W2,
               const float* __restrict__ wf_W1, const float* __restrict__ hb_W,
               const float* __restrict__ v_W1,  const float* __restrict__ wf_W2,
               short* __restrict__ fb)
{
    const int blk = blockIdx.x, lane = threadIdx.x;
    const int quad = lane >> 4, l16 = lane & 15;
    bs8 v;
    if (blk < 8) {
        // M[k][n] = dot(Wq[k,:], Wk[n,:]) * INV_S, k = ks*32+quad*8+j
        const int ks = blk >> 2, n = (blk & 3) * 16 + l16;
        float acc[8] = {0.f,0.f,0.f,0.f,0.f,0.f,0.f,0.f};
        const float4* wk4 = (const float4*)(Wk + n * 128);
        for (int t4 = 0; t4 < 32; ++t4) {
            const float4 wk = wk4[t4];
            #pragma unroll
            for (int j = 0; j < 8; ++j) {
                const float4 wq = *(const float4*)(Wq + (ks * 32 + quad * 8 + j) * 128 + t4 * 4);
                acc[j] += wq.x * wk.x + wq.y * wk.y + wq.z * wk.z + wq.w * wk.w;
            }
        }
        #pragma unroll
        for (int j = 0; j < 8; ++j) v[j] = f2bf(acc[j] * INV_S);
    } else if (blk < 16) {
        const bool en = (blk >= 12);
        const float* W = en ? W_en : W_al;
        const int Krows = en ? 16 : 32;
        const int n = ((blk - (en ? 12 : 8)) & 3) * 16 + l16;
        #pragma unroll
        for (int j = 0; j < 8; ++j) {
            const int k = quad * 8 + j;
            v[j] = (k < Krows) ? f2bf(W[k * 64 + n]) : (short)0;
        }
    } else if (blk < 32) {
        const int t = blk - 16, ks = t >> 2, n = (t & 3) * 16 + l16;
        #pragma unroll
        for (int j = 0; j < 8; ++j)
            v[j] = f2bf(w1_W1[(ks * 32 + quad * 8 + j) * 64 + n]);
    } else if (blk < 36) {
        const int t = blk - 32, ks = t >> 1, n = (t & 1) * 16 + l16;
        #pragma unroll
        for (int j = 0; j < 8; ++j)
            v[j] = f2bf(w1_W2[(ks * 32 + quad * 8 + j) * 32 + n]);
    } else if (blk < 38) {
        // vq col tiles: B[k][0] = (Wq bk)[ks*32+k] * INV_S, other cols 0
        const int ks = blk - 36;
        float acc[8] = {0.f,0.f,0.f,0.f,0.f,0.f,0.f,0.f};
        const float4* bk4 = (const float4*)bk;
        for (int t4 = 0; t4 < 32; ++t4) {
            const float4 b = bk4[t4];
            #pragma unroll
            for (int j = 0; j < 8; ++j) {
                const float4 wq = *(const float4*)(Wq + (ks * 32 + quad * 8 + j) * 128 + t4 * 4);
                acc[j] += wq.x * b.x + wq.y * b.y + wq.z * b.z + wq.w * b.w;
            }
        }
        #pragma unroll
        for (int j = 0; j < 8; ++j)
            v[j] = (l16 == 0) ? f2bf(acc[j] * INV_S) : (short)0;
    } else if (blk < 54) {          // bigW1 [64 x 128] = [wf_W1 | hb_W | v_W1]
        const int t = blk - 38, ks = t >> 3, n = (t & 7) * 16 + l16;
        #pragma unroll
        for (int j = 0; j < 8; ++j) {
            const int k = ks * 32 + quad * 8 + j;
            float w;
            if (n < 64)       w = wf_W1[k * 64 + n];
            else if (n < 96)  w = hb_W[k * 32 + (n - 64)];
            else              w = v_W1[k * 32 + (n - 96)];
            v[j] = f2bf(w);
        }
    } else {                        // 54-57: wf_W2 [64 x 32]
        const int t = blk - 54, ks = t >> 1, n = (t & 1) * 16 + l16;
        #pragma unroll
        for (int j = 0; j < 8; ++j)
            v[j] = f2bf(wf_W2[(ks * 32 + quad * 8 + j) * 32 + n]);
    }
    *(bs8*)&fb[(size_t)blk * 512 + lane * 8] = v;
}

// ---------------- main: 2 waves/block, 2 sites/wave ----------------
struct __align__(16) WaveLds {
    short ent[2][16][72];  // persistent bf16 embeds (144B rows)
    short scr[2][16][72];  // t per site; scr[0] later = hall
    short aoutb[2][64];
    short hb16[2][64];
    float qs[2][8];
};

__global__ __launch_bounds__(128, 4)
void qmix_main(const float* __restrict__ agent_qs,
               const float* __restrict__ ally, const float* __restrict__ enemy,
               const float* __restrict__ b_al, const float* __restrict__ b_en,
               const float* __restrict__ w1_b1, const float* __restrict__ w1_b2,
               const float* __restrict__ wf_b1, const float* __restrict__ wf_b2,
               const float* __restrict__ hb_b,  const float* __restrict__ v_b1,
               const float* __restrict__ v_W2,  const float* __restrict__ v_b2,
               const short* __restrict__ fb,
               float* __restrict__ out)
{
    const int w    = threadIdx.x >> 6;
    const int lane = threadIdx.x & 63;
    const int quad = lane >> 4, l16 = lane & 15;
    const int half = lane >> 5;      // final-stage site of this lane
    const int qh   = quad & 1;
    const int siteA = blockIdx.x * 4 + w * 2;   // sites siteA, siteA+1

    __shared__ WaveLds lds[2];
    WaveLds& L = lds[w];

    if (lane < 16)
        L.qs[lane >> 3][lane & 7] =
            agent_qs[(size_t)(siteA + (lane >> 3)) * 8 + (lane & 7)];

    // ---- encoders per site: D rows 0-7 ally, 8-15 enemy ----
    #pragma unroll
    for (int s = 0; s < 2; ++s) {
        const int site = siteA + s;
        bs8 a_al = {0,0,0,0,0,0,0,0}, a_en = {0,0,0,0,0,0,0,0};
        if (l16 < 8) {
            const float* pa = ally + ((size_t)l16 * BS_ + site) * 32 + quad * 8;
            const float4 f0 = *(const float4*)pa, f1 = *(const float4*)(pa + 4);
            a_al[0]=f2bf(f0.x); a_al[1]=f2bf(f0.y); a_al[2]=f2bf(f0.z); a_al[3]=f2bf(f0.w);
            a_al[4]=f2bf(f1.x); a_al[5]=f2bf(f1.y); a_al[6]=f2bf(f1.z); a_al[7]=f2bf(f1.w);
        } else if (quad < 2) {   // enemy K=16: quads 0,1 only
            const float* pe = enemy + ((size_t)(l16 - 8) * BS_ + site) * 16 + quad * 8;
            const float4 f0 = *(const float4*)pe, f1 = *(const float4*)(pe + 4);
            a_en[0]=f2bf(f0.x); a_en[1]=f2bf(f0.y); a_en[2]=f2bf(f0.z); a_en[3]=f2bf(f0.w);
            a_en[4]=f2bf(f1.x); a_en[5]=f2bf(f1.y); a_en[6]=f2bf(f1.z); a_en[7]=f2bf(f1.w);
        }
        #pragma unroll
        for (int n0t = 0; n0t < 4; ++n0t) {
            f4 acc = {0.f, 0.f, 0.f, 0.f};
            acc = MFMA(a_al, LOADB(8 + n0t), acc);
            acc = MFMA(a_en, LOADB(12 + n0t), acc);
            const int d = n0t * 16 + l16;
            const float bal = b_al[d], ben = b_en[d];
            #pragma unroll
            for (int r = 0; r < 4; ++r) {
                const int row = quad * 4 + r;
                L.ent[s][row][d] = f2bf(acc[r] + (row < 8 ? bal : ben));
            }
        }
    }
    __syncthreads();   // B1: ent ready (persists whole kernel)

    // ---- per-site A-frags of ent ----
    bs8 ae0s[2], ae1s[2];
    #pragma unroll
    for (int s = 0; s < 2; ++s) {
        ae0s[s] = *(const bs8*)&L.ent[s][l16][quad * 8];
        ae1s[s] = *(const bs8*)&L.ent[s][l16][32 + quad * 8];
    }

    // ---- t = ent @ M -> scr ; pq = ent @ vq ----
    f4 pqs[2];
    #pragma unroll
    for (int s = 0; s < 2; ++s) {
        f4 pq = {0.f, 0.f, 0.f, 0.f};
        pq = MFMA(ae0s[s], LOADB(36), pq);
        pq = MFMA(ae1s[s], LOADB(37), pq);
        pqs[s] = pq;
        #pragma unroll
        for (int n0t = 0; n0t < 4; ++n0t) {
            f4 acc = {0.f, 0.f, 0.f, 0.f};
            acc = MFMA(ae0s[s], LOADB(0 + n0t), acc);
            acc = MFMA(ae1s[s], LOADB(4 + n0t), acc);
            const int d = n0t * 16 + l16;
            #pragma unroll
            for (int r = 0; r < 4; ++r) L.scr[s][quad * 4 + r][d] = f2bf(acc[r]);
        }
    }
    __syncthreads();   // B2: t ready

    // ---- energy + softmax + attn_out per site ----
    #pragma unroll
    for (int s = 0; s < 2; ++s) {
        f4 eacc = {0.f, 0.f, 0.f, 0.f};
        {
            const bs8 at0 = *(const bs8*)&L.scr[s][l16][quad * 8];
            const bs8 at1 = *(const bs8*)&L.scr[s][l16][32 + quad * 8];
            eacc = MFMA(at0, ae0s[s], eacc);
            eacc = MFMA(at1, ae1s[s], eacc);
            const int src = lane & 48;
            #pragma unroll
            for (int r = 0; r < 4; ++r) eacc[r] += __shfl(pqs[s][r], src, 64);
        }
        float cmax = fmaxf(fmaxf(eacc[0], eacc[1]), fmaxf(eacc[2], eacc[3]));
        cmax = fmaxf(cmax, __shfl_xor(cmax, 16, 64));
        cmax = fmaxf(cmax, __shfl_xor(cmax, 32, 64));
        float er[4], csum = 0.f;
        #pragma unroll
        for (int r = 0; r < 4; ++r) { er[r] = __expf(eacc[r] - cmax); csum += er[r]; }
        csum += __shfl_xor(csum, 16, 64);
        csum += __shfl_xor(csum, 32, 64);
        const float inv = 1.f / csum;
        float amean[4];
        #pragma unroll
        for (int r = 0; r < 4; ++r) {
            float p = er[r] * inv;
            p += __shfl_xor(p, 1, 64);
            p += __shfl_xor(p, 2, 64);
            p += __shfl_xor(p, 4, 64);
            p += __shfl_xor(p, 8, 64);
            amean[r] = p * (1.f / 16.f);
        }
        // attn_out from LDS bf16 ent (C-layout positions; transient reads)
        #pragma unroll
        for (int n0t = 0; n0t < 4; ++n0t) {
            const int d = n0t * 16 + l16;
            float ap = amean[0] * bf2f(L.ent[s][quad * 4 + 0][d])
                     + amean[1] * bf2f(L.ent[s][quad * 4 + 1][d])
                     + amean[2] * bf2f(L.ent[s][quad * 4 + 2][d])
                     + amean[3] * bf2f(L.ent[s][quad * 4 + 3][d]);
            ap += __shfl_xor(ap, 16, 64);
            ap += __shfl_xor(ap, 32, 64);
            if (quad == 0) L.aoutb[s][d] = f2bf(ap);
        }
    }
    __syncthreads();   // B3: aoutb ready

    // ---- stacked aout A-frag: rows 0-7 site0, 8-15 site1 ----
    const short* aoP = L.aoutb[l16 >> 3];
    const bs8 aab0 = *(const bs8*)&aoP[quad * 8];
    const bs8 aab1 = *(const bs8*)&aoP[32 + quad * 8];

    // ---- pass1: x = aout @ [wf_W1 | hb_W | v_W1], both sites stacked ----
    float xm[8];
    #pragma unroll
    for (int n0t = 0; n0t < 8; ++n0t) {
        f4 acc = {0.f, 0.f, 0.f, 0.f};
        acc = MFMA(aab0, LOADB(38 + n0t), acc);
        acc = MFMA(aab1, LOADB(46 + n0t), acc);
        xm[n0t] = acc[0];   // rows within a site identical
    }
    #pragma unroll
    for (int n0t = 0; n0t < 4; ++n0t) {
        const int t = n0t * 16 + l16;
        L.hb16[half][t] = f2bf(fmaxf(xm[n0t] + wf_b1[t], 0.f));
    }
    const int m32 = lane & 31;
    const float b1m = xm[4 + qh] + hb_b[m32];
    float vsum;
    {
        float hv = fmaxf(xm[6 + qh] + v_b1[m32], 0.f) * v_W2[m32];
        hv += __shfl_xor(hv, 1, 64);
        hv += __shfl_xor(hv, 2, 64);
        hv += __shfl_xor(hv, 4, 64);
        hv += __shfl_xor(hv, 8, 64);
        hv += __shfl_xor(hv, 16, 64);
        vsum = hv;   // per-half v_s
    }
    __syncthreads();   // B4: hb16 ready

    // ---- wf layer2, both sites stacked ----
    float wfm;
    {
        const short* hfP = L.hb16[l16 >> 3];
        const bs8 hf0 = *(const bs8*)&hfP[quad * 8];
        const bs8 hf1 = *(const bs8*)&hfP[32 + quad * 8];
        f4 acc0 = {0.f, 0.f, 0.f, 0.f};
        acc0 = MFMA(hf0, LOADB(54), acc0);
        acc0 = MFMA(hf1, LOADB(56), acc0);
        f4 acc1 = {0.f, 0.f, 0.f, 0.f};
        acc1 = MFMA(hf0, LOADB(55), acc1);
        acc1 = MFMA(hf1, LOADB(57), acc1);
        wfm = fabsf((qh ? acc1[0] : acc0[0]) + wf_b2[m32]);
    }

    // ---- agent hypernet L1, both sites stacked (ag read at use-time) ----
    {
        const short (*entP)[72] = (l16 < 8) ? L.ent[0] : L.ent[1];
        const bs8 ag0 = *(const bs8*)&entP[l16 & 7][quad * 8];
        const bs8 ag1 = *(const bs8*)&entP[l16 & 7][32 + quad * 8];
        #pragma unroll
        for (int n0t = 0; n0t < 4; ++n0t) {
            f4 acc = {0.f, 0.f, 0.f, 0.f};
            acc = MFMA(aab0, LOADB(16 + 0 + n0t), acc);
            acc = MFMA(aab1, LOADB(16 + 4 + n0t), acc);
            acc = MFMA(ag0,  LOADB(16 + 8 + n0t), acc);
            acc = MFMA(ag1,  LOADB(16 + 12 + n0t), acc);
            const int d = n0t * 16 + l16;
            const float b1v = w1_b1[d];
            #pragma unroll
            for (int r = 0; r < 4; ++r)
                L.scr[0][quad * 4 + r][d] = f2bf(fmaxf(acc[r] + b1v, 0.f));  // hall
        }
    }
    __syncthreads();   // B5: hall ready

    // ---- hypernet L2 + mixing partials (rows = stacked agents) ----
    float pm;
    {
        const bs8 ha0 = *(const bs8*)&L.scr[0][l16][quad * 8];
        const bs8 ha1 = *(const bs8*)&L.scr[0][l16][32 + quad * 8];
        const float* qsv = L.qs[half];
        float p0 = 0.f, p1 = 0.f;
        #pragma unroll
        for (int n0t = 0; n0t < 2; ++n0t) {
            f4 acc = {0.f, 0.f, 0.f, 0.f};
            acc = MFMA(ha0, LOADB(32 + 0 + n0t), acc);
            acc = MFMA(ha1, LOADB(32 + 2 + n0t), acc);
            const float b2v = w1_b2[n0t * 16 + l16];
            float p = 0.f;
            #pragma unroll
            for (int r = 0; r < 4; ++r)
                p += qsv[qh * 4 + r] * fabsf(acc[r] + b2v);
            if (n0t == 0) p0 = p; else p1 = p;
        }
        p0 += __shfl_xor(p0, 16, 64);   // agents 0-3 + 4-7 within each site
        p1 += __shfl_xor(p1, 16, 64);
        pm = qh ? p1 : p0;               // lane's col m32 value
    }

    // ---- elu, mix, half-reduce (lanes 0-31 site0, 32-63 site1) ----
    float hp = pm + b1m;
    hp = (hp > 0.f) ? hp : (__expf(hp) - 1.f);
    float contrib = hp * wfm;
    contrib += __shfl_xor(contrib, 1, 64);
    contrib += __shfl_xor(contrib, 2, 64);
    contrib += __shfl_xor(contrib, 4, 64);
    contrib += __shfl_xor(contrib, 8, 64);
    contrib += __shfl_xor(contrib, 16, 64);
    if ((lane & 31) == 0)
        out[siteA + half] = contrib + vsum + v_b2[0];
}

extern "C" void kernel_launch(void* const* d_in, const int* in_sizes, int n_in,
                              void* d_out, int out_size, void* d_ws, size_t ws_size,
                              hipStream_t stream) {
    const float* p[25];
    for (int i = 0; i < 25; ++i) p[i] = (const float*)d_in[i];
    // 0 agent_qs 1 ally 2 enemy 3 W_al 4 b_al 5 W_en 6 b_en 7 Wq 8 bq 9 Wk 10 bk
    // 11 w1_W1 12 w1_b1 13 w1_W2 14 w1_b2 15 wf_W1 16 wf_b1 17 wf_W2 18 wf_b2
    // 19 hb_W 20 hb_b 21 v_W1 22 v_b1 23 v_W2 24 v_b2
    short* fb = (short*)d_ws;   // 58 tiles * 512 bf16 = 59392 B

    qmix_pack<<<58, 64, 0, stream>>>(p[7], p[9], p[10], p[3], p[5],
                                     p[11], p[13], p[15], p[19], p[21], p[17], fb);
    qmix_main<<<BS_ / 4, 128, 0, stream>>>(
        p[0], p[1], p[2], p[4], p[6], p[12], p[14],
        p[16], p[18], p[20], p[22], p[23], p[24],
        fb, (float*)d_out);
}

// Round 12
// 148.702 us; speedup vs baseline: 6.8288x; 1.0305x over previous
//
#include <hip/hip_runtime.h>
#include <hip/hip_bf16.h>

// QMixer forward, MI355X gfx950. fp32 in/out, bf16 MFMA for all matmul blocks.
// B=128 S=128 A=8 En=8 E=16 NFal=32 NFen=16 D=64 Da=128 M=32 H=64.
// Algebra (verified R4): softmax over query axis i cancels per-column-j terms:
//   energy[i][j] = e_i (Wq Wk^T/sqrt(Da)) e_j^T + e_i.(Wq bk)/sqrt(Da)
// R12 (DS-pipe cuts; main was LDS-pipe-bound):
//  - t/hall computed TRANSPOSED (t^T = M^T@ent^T, hall^T = w1_W1^T@emi^T).
//    B-frag-of-W == A-frag-of-W^T in these layouts, so the SAME packed tiles
//    serve as A; outputs land row-contiguous -> ds_write_b64 (48 b16 -> 12 b64).
//  - __syncthreads -> compiler fences only (waves share no LDS; same-wave DS
//    ops are pipe-ordered on CDNA).
//  - attn_out from packed-bf16 regs (encb); qs via global; distributed
//    aoutb/hb16 writes; softmax without max-sub; v-net fused into final reduce.
// MFMA 16x16x32 layouts (HW-verified): A[m=lane&15][k=quad*8+j],
// B[k=quad*8+j][n=lane&15], C/D[row=quad*4+r][col=lane&15].

#define B_   128
#define S_   128
#define BS_  (B_ * S_)
#define INV_S 0.08838834764831845f  // 1/sqrt(128)

typedef short bs8 __attribute__((ext_vector_type(8)));
typedef short bs4 __attribute__((ext_vector_type(4)));
typedef float f4  __attribute__((ext_vector_type(4)));

#define MFMA(a, b, c) __builtin_amdgcn_mfma_f32_16x16x32_bf16((a), (b), (c), 0, 0, 0)
#define LOADB(t) (*(const bs8*)&fb[(size_t)(t) * 512 + lane * 8])
#define FENCE() asm volatile("" ::: "memory")

__device__ __forceinline__ short f2bf(float f) {
    union { float f; unsigned u; } v; v.f = f;
    unsigned r = v.u + 0x7fffu + ((v.u >> 16) & 1u);   // RNE
    return (short)(r >> 16);
}
__device__ __forceinline__ unsigned f2bf2(float lo, float hi) {
    return (unsigned)(unsigned short)f2bf(lo) | ((unsigned)(unsigned short)f2bf(hi) << 16);
}
__device__ __forceinline__ float bf2f_lo(unsigned u) {
    union { unsigned u; float f; } v; v.u = u << 16; return v.f;
}
__device__ __forceinline__ float bf2f_hi(unsigned u) {
    union { unsigned u; float f; } v; v.u = u & 0xffff0000u; return v.f;
}

// ---------------- pack: bf16 B-fragment tiles (unchanged from R11) ----------------
// frag tile = 512 bf16: [lane][j], elem j = W[k = ks*32+quad*8+j][n = n0+l16]
// tiles: 0-7 M | 8-11 W_al | 12-15 W_en(K=16 pad) | 16-31 w1_W1 | 32-35 w1_W2 |
//        36-37 vq col | 38-53 bigW1=[wf_W1|hb_W|v_W1] | 54-57 wf_W2
__global__ __launch_bounds__(64)
void qmix_pack(const float* __restrict__ Wq,   const float* __restrict__ Wk,
               const float* __restrict__ bk,
               const float* __restrict__ W_al, const float* __restrict__ W_en,
               const float* __restrict__ w1_W1, const float* __restrict__ w1_W2,
               const float* __restrict__ wf_W1, const float* __restrict__ hb_W,
               const float* __restrict__ v_W1,  const float* __restrict__ wf_W2,
               short* __restrict__ fb)
{
    const int blk = blockIdx.x, lane = threadIdx.x;
    const int quad = lane >> 4, l16 = lane & 15;
    bs8 v;
    if (blk < 8) {
        const int ks = blk >> 2, n = (blk & 3) * 16 + l16;
        float acc[8] = {0.f,0.f,0.f,0.f,0.f,0.f,0.f,0.f};
        const float4* wk4 = (const float4*)(Wk + n * 128);
        for (int t4 = 0; t4 < 32; ++t4) {
            const float4 wk = wk4[t4];
            #pragma unroll
            for (int j = 0; j < 8; ++j) {
                const float4 wq = *(const float4*)(Wq + (ks * 32 + quad * 8 + j) * 128 + t4 * 4);
                acc[j] += wq.x * wk.x + wq.y * wk.y + wq.z * wk.z + wq.w * wk.w;
            }
        }
        #pragma unroll
        for (int j = 0; j < 8; ++j) v[j] = f2bf(acc[j] * INV_S);
    } else if (blk < 16) {
        const bool en = (blk >= 12);
        const float* W = en ? W_en : W_al;
        const int Krows = en ? 16 : 32;
        const int n = ((blk - (en ? 12 : 8)) & 3) * 16 + l16;
        #pragma unroll
        for (int j = 0; j < 8; ++j) {
            const int k = quad * 8 + j;
            v[j] = (k < Krows) ? f2bf(W[k * 64 + n]) : (short)0;
        }
    } else if (blk < 32) {
        const int t = blk - 16, ks = t >> 2, n = (t & 3) * 16 + l16;
        #pragma unroll
        for (int j = 0; j < 8; ++j)
            v[j] = f2bf(w1_W1[(ks * 32 + quad * 8 + j) * 64 + n]);
    } else if (blk < 36) {
        const int t = blk - 32, ks = t >> 1, n = (t & 1) * 16 + l16;
        #pragma unroll
        for (int j = 0; j < 8; ++j)
            v[j] = f2bf(w1_W2[(ks * 32 + quad * 8 + j) * 32 + n]);
    } else if (blk < 38) {
        const int ks = blk - 36;
        float acc[8] = {0.f,0.f,0.f,0.f,0.f,0.f,0.f,0.f};
        const float4* bk4 = (const float4*)bk;
        for (int t4 = 0; t4 < 32; ++t4) {
            const float4 b = bk4[t4];
            #pragma unroll
            for (int j = 0; j < 8; ++j) {
                const float4 wq = *(const float4*)(Wq + (ks * 32 + quad * 8 + j) * 128 + t4 * 4);
                acc[j] += wq.x * b.x + wq.y * b.y + wq.z * b.z + wq.w * b.w;
            }
        }
        #pragma unroll
        for (int j = 0; j < 8; ++j)
            v[j] = (l16 == 0) ? f2bf(acc[j] * INV_S) : (short)0;
    } else if (blk < 54) {
        const int t = blk - 38, ks = t >> 3, n = (t & 7) * 16 + l16;
        #pragma unroll
        for (int j = 0; j < 8; ++j) {
            const int k = ks * 32 + quad * 8 + j;
            float w;
            if (n < 64)       w = wf_W1[k * 64 + n];
            else if (n < 96)  w = hb_W[k * 32 + (n - 64)];
            else              w = v_W1[k * 32 + (n - 96)];
            v[j] = f2bf(w);
        }
    } else {
        const int t = blk - 54, ks = t >> 1, n = (t & 1) * 16 + l16;
        #pragma unroll
        for (int j = 0; j < 8; ++j)
            v[j] = f2bf(wf_W2[(ks * 32 + quad * 8 + j) * 32 + n]);
    }
    *(bs8*)&fb[(size_t)blk * 512 + lane * 8] = v;
}

// ---------------- main: 2 waves/block, 2 sites/wave, zero barriers ----------------
struct __align__(16) WaveLds {
    short ent[2][16][72];  // persistent bf16 embeds (144B rows)
    short scr[2][16][72];  // t^T per site; scr[0] later = hall^T
    short aoutb[2][64];
    short hb16[2][64];
};

__global__ __launch_bounds__(128, 4)
void qmix_main(const float* __restrict__ agent_qs,
               const float* __restrict__ ally, const float* __restrict__ enemy,
               const float* __restrict__ b_al, const float* __restrict__ b_en,
               const float* __restrict__ w1_b1, const float* __restrict__ w1_b2,
               const float* __restrict__ wf_b1, const float* __restrict__ wf_b2,
               const float* __restrict__ hb_b,  const float* __restrict__ v_b1,
               const float* __restrict__ v_W2,  const float* __restrict__ v_b2,
               const short* __restrict__ fb,
               float* __restrict__ out)
{
    const int w    = threadIdx.x >> 6;
    const int lane = threadIdx.x & 63;
    const int quad = lane >> 4, l16 = lane & 15;
    const int half = lane >> 5;
    const int qh   = quad & 1;
    const int siteA = blockIdx.x * 4 + w * 2;

    __shared__ WaveLds lds[2];
    WaveLds& L = lds[w];

    unsigned encb[2][4][2];   // packed bf16 fp-embeds: [site][n0t][pair of rows]

    // ---- encoders per site: D rows 0-7 ally, 8-15 enemy ----
    #pragma unroll
    for (int s = 0; s < 2; ++s) {
        const int site = siteA + s;
        bs8 a_al = {0,0,0,0,0,0,0,0}, a_en = {0,0,0,0,0,0,0,0};
        if (l16 < 8) {
            const float* pa = ally + ((size_t)l16 * BS_ + site) * 32 + quad * 8;
            const float4 f0 = *(const float4*)pa, f1 = *(const float4*)(pa + 4);
            a_al[0]=f2bf(f0.x); a_al[1]=f2bf(f0.y); a_al[2]=f2bf(f0.z); a_al[3]=f2bf(f0.w);
            a_al[4]=f2bf(f1.x); a_al[5]=f2bf(f1.y); a_al[6]=f2bf(f1.z); a_al[7]=f2bf(f1.w);
        } else if (quad < 2) {
            const float* pe = enemy + ((size_t)(l16 - 8) * BS_ + site) * 16 + quad * 8;
            const float4 f0 = *(const float4*)pe, f1 = *(const float4*)(pe + 4);
            a_en[0]=f2bf(f0.x); a_en[1]=f2bf(f0.y); a_en[2]=f2bf(f0.z); a_en[3]=f2bf(f0.w);
            a_en[4]=f2bf(f1.x); a_en[5]=f2bf(f1.y); a_en[6]=f2bf(f1.z); a_en[7]=f2bf(f1.w);
        }
        #pragma unroll
        for (int n0t = 0; n0t < 4; ++n0t) {
            f4 acc = {0.f, 0.f, 0.f, 0.f};
            acc = MFMA(a_al, LOADB(8 + n0t), acc);
            acc = MFMA(a_en, LOADB(12 + n0t), acc);
            const int d = n0t * 16 + l16;
            const float bal = b_al[d], ben = b_en[d];
            float vv[4];
            #pragma unroll
            for (int r = 0; r < 4; ++r) {
                const int row = quad * 4 + r;
                vv[r] = acc[r] + (row < 8 ? bal : ben);
                L.ent[s][row][d] = f2bf(vv[r]);
            }
            encb[s][n0t][0] = f2bf2(vv[0], vv[1]);
            encb[s][n0t][1] = f2bf2(vv[2], vv[3]);
        }
    }
    FENCE();

    // ---- per-site A-frags of ent (also B-frags of ent^T) ----
    bs8 ae0s[2], ae1s[2];
    #pragma unroll
    for (int s = 0; s < 2; ++s) {
        ae0s[s] = *(const bs8*)&L.ent[s][l16][quad * 8];
        ae1s[s] = *(const bs8*)&L.ent[s][l16][32 + quad * 8];
    }

    // ---- t^T = M^T @ ent^T (A = M tiles reused; b64 row-contiguous writes) ----
    f4 pqs[2];
    #pragma unroll
    for (int s = 0; s < 2; ++s) {
        f4 pq = {0.f, 0.f, 0.f, 0.f};
        pq = MFMA(ae0s[s], LOADB(36), pq);
        pq = MFMA(ae1s[s], LOADB(37), pq);
        pqs[s] = pq;
        #pragma unroll
        for (int mdt = 0; mdt < 4; ++mdt) {
            f4 acc = {0.f, 0.f, 0.f, 0.f};
            acc = MFMA(LOADB(0 + mdt), ae0s[s], acc);
            acc = MFMA(LOADB(4 + mdt), ae1s[s], acc);
            bs4 tv;
            #pragma unroll
            for (int r = 0; r < 4; ++r) tv[r] = f2bf(acc[r]);
            *(bs4*)&L.scr[s][l16][mdt * 16 + quad * 4] = tv;
        }
    }
    FENCE();

    // ---- energy + softmax (no max-sub; |energy|<<1) + attn_out per site ----
    #pragma unroll
    for (int s = 0; s < 2; ++s) {
        f4 eacc = {0.f, 0.f, 0.f, 0.f};
        {
            const bs8 at0 = *(const bs8*)&L.scr[s][l16][quad * 8];
            const bs8 at1 = *(const bs8*)&L.scr[s][l16][32 + quad * 8];
            eacc = MFMA(at0, ae0s[s], eacc);
            eacc = MFMA(at1, ae1s[s], eacc);
            const int src = lane & 48;
            #pragma unroll
            for (int r = 0; r < 4; ++r) eacc[r] += __shfl(pqs[s][r], src, 64);
        }
        float er[4], csum = 0.f;
        #pragma unroll
        for (int r = 0; r < 4; ++r) { er[r] = __expf(eacc[r]); csum += er[r]; }
        csum += __shfl_xor(csum, 16, 64);
        csum += __shfl_xor(csum, 32, 64);
        const float inv = 1.f / csum;
        float amean[4];
        #pragma unroll
        for (int r = 0; r < 4; ++r) {
            float p = er[r] * inv;
            p += __shfl_xor(p, 1, 64);
            p += __shfl_xor(p, 2, 64);
            p += __shfl_xor(p, 4, 64);
            p += __shfl_xor(p, 8, 64);
            amean[r] = p * (1.f / 16.f);
        }
        // attn_out from packed regs; each quad keeps its own n0t column
        float sel = 0.f;
        #pragma unroll
        for (int n0t = 0; n0t < 4; ++n0t) {
            float ap = amean[0] * bf2f_lo(encb[s][n0t][0])
                     + amean[1] * bf2f_hi(encb[s][n0t][0])
                     + amean[2] * bf2f_lo(encb[s][n0t][1])
                     + amean[3] * bf2f_hi(encb[s][n0t][1]);
            ap += __shfl_xor(ap, 16, 64);
            ap += __shfl_xor(ap, 32, 64);
            sel = (n0t == quad) ? ap : sel;
        }
        L.aoutb[s][quad * 16 + l16] = f2bf(sel);   // one write instr per site
    }
    FENCE();

    // ---- stacked aout + agent A/B frags ----
    const short* aoP = L.aoutb[l16 >> 3];
    const bs8 aab0 = *(const bs8*)&aoP[quad * 8];
    const bs8 aab1 = *(const bs8*)&aoP[32 + quad * 8];
    const short (*entP)[72] = (l16 < 8) ? L.ent[0] : L.ent[1];
    const bs8 ag0 = *(const bs8*)&entP[l16 & 7][quad * 8];
    const bs8 ag1 = *(const bs8*)&entP[l16 & 7][32 + quad * 8];

    // ---- pass1: x = aout @ [wf_W1 | hb_W | v_W1], both sites stacked ----
    float xm[8];
    #pragma unroll
    for (int n0t = 0; n0t < 8; ++n0t) {
        f4 acc = {0.f, 0.f, 0.f, 0.f};
        acc = MFMA(aab0, LOADB(38 + n0t), acc);
        acc = MFMA(aab1, LOADB(46 + n0t), acc);
        xm[n0t] = acc[0];   // rows within a site identical
    }
    // wf hidden: distributed writes (2 per lane)
    #pragma unroll
    for (int k = 0; k < 2; ++k) {
        const int n0t = qh * 2 + k;
        const int c = n0t * 16 + l16;
        L.hb16[half][c] = f2bf(fmaxf(xm[n0t] + wf_b1[c], 0.f));
    }
    const int m32 = lane & 31;
    const float b1m = xm[4 + qh] + hb_b[m32];
    const float hv = fmaxf(xm[6 + qh] + v_b1[m32], 0.f) * v_W2[m32];
    FENCE();

    // ---- wf layer2, both sites stacked ----
    float wfm;
    {
        const short* hfP = L.hb16[l16 >> 3];
        const bs8 hf0 = *(const bs8*)&hfP[quad * 8];
        const bs8 hf1 = *(const bs8*)&hfP[32 + quad * 8];
        f4 acc0 = {0.f, 0.f, 0.f, 0.f};
        acc0 = MFMA(hf0, LOADB(54), acc0);
        acc0 = MFMA(hf1, LOADB(56), acc0);
        f4 acc1 = {0.f, 0.f, 0.f, 0.f};
        acc1 = MFMA(hf0, LOADB(55), acc1);
        acc1 = MFMA(hf1, LOADB(57), acc1);
        wfm = fabsf((qh ? acc1[0] : acc0[0]) + wf_b2[m32]);
    }

    // ---- hall^T = w1_W1^T @ emi^T (A = w1_W1 tiles reused; b64 writes) ----
    #pragma unroll
    for (int mt = 0; mt < 4; ++mt) {
        f4 acc = {0.f, 0.f, 0.f, 0.f};
        acc = MFMA(LOADB(16 + mt),      aab0, acc);
        acc = MFMA(LOADB(16 + 4 + mt),  aab1, acc);
        acc = MFMA(LOADB(16 + 8 + mt),  ag0,  acc);
        acc = MFMA(LOADB(16 + 12 + mt), ag1,  acc);
        const float4 b1v4 = *(const float4*)&w1_b1[mt * 16 + quad * 4];
        bs4 hw;
        hw[0] = f2bf(fmaxf(acc[0] + b1v4.x, 0.f));
        hw[1] = f2bf(fmaxf(acc[1] + b1v4.y, 0.f));
        hw[2] = f2bf(fmaxf(acc[2] + b1v4.z, 0.f));
        hw[3] = f2bf(fmaxf(acc[3] + b1v4.w, 0.f));
        *(bs4*)&L.scr[0][l16][mt * 16 + quad * 4] = hw;
    }
    FENCE();

    // ---- hypernet L2 + mixing partials (rows = stacked agents) ----
    float pm;
    {
        const bs8 ha0 = *(const bs8*)&L.scr[0][l16][quad * 8];
        const bs8 ha1 = *(const bs8*)&L.scr[0][l16][32 + quad * 8];
        const float4 qsv4 = *(const float4*)&agent_qs[(size_t)(siteA + half) * 8 + qh * 4];
        float p0 = 0.f, p1 = 0.f;
        #pragma unroll
        for (int n0t = 0; n0t < 2; ++n0t) {
            f4 acc = {0.f, 0.f, 0.f, 0.f};
            acc = MFMA(ha0, LOADB(32 + n0t), acc);
            acc = MFMA(ha1, LOADB(34 + n0t), acc);
            const float b2v = w1_b2[n0t * 16 + l16];
            float p = qsv4.x * fabsf(acc[0] + b2v) + qsv4.y * fabsf(acc[1] + b2v)
                    + qsv4.z * fabsf(acc[2] + b2v) + qsv4.w * fabsf(acc[3] + b2v);
            if (n0t == 0) p0 = p; else p1 = p;
        }
        p0 += __shfl_xor(p0, 16, 64);
        p1 += __shfl_xor(p1, 16, 64);
        pm = qh ? p1 : p0;
    }

    // ---- elu, mix (+v partial), half-reduce ----
    float hp = pm + b1m;
    hp = (hp > 0.f) ? hp : (__expf(hp) - 1.f);
    float contrib = hp * wfm + hv;
    contrib += __shfl_xor(contrib, 1, 64);
    contrib += __shfl_xor(contrib, 2, 64);
    contrib += __shfl_xor(contrib, 4, 64);
    contrib += __shfl_xor(contrib, 8, 64);
    contrib += __shfl_xor(contrib, 16, 64);
    if ((lane & 31) == 0)
        out[siteA + half] = contrib + v_b2[0];
}

extern "C" void kernel_launch(void* const* d_in, const int* in_sizes, int n_in,
                              void* d_out, int out_size, void* d_ws, size_t ws_size,
                              hipStream_t stream) {
    const float* p[25];
    for (int i = 0; i < 25; ++i) p[i] = (const float*)d_in[i];
    // 0 agent_qs 1 ally 2 enemy 3 W_al 4 b_al 5 W_en 6 b_en 7 Wq 8 bq 9 Wk 10 bk
    // 11 w1_W1 12 w1_b1 13 w1_W2 14 w1_b2 15 wf_W1 16 wf_b1 17 wf_W2 18 wf_b2
    // 19 hb_W 20 hb_b 21 v_W1 22 v_b1 23 v_W2 24 v_b2
    short* fb = (short*)d_ws;   // 58 tiles * 512 bf16 = 59392 B

    qmix_pack<<<58, 64, 0, stream>>>(p[7], p[9], p[10], p[3], p[5],
                                     p[11], p[13], p[15], p[19], p[21], p[17], fb);
    qmix_main<<<BS_ / 4, 128, 0, stream>>>(
        p[0], p[1], p[2], p[4], p[6], p[12], p[14],
        p[16], p[18], p[20], p[22], p[23], p[24],
        fb, (float*)d_out);
}